// Round 1
// baseline (15290.738 us; speedup 1.0000x reference)
//
#include <hip/hip_runtime.h>
#include <hip/hip_bf16.h>
#include <math.h>

#define HD   128
#define EIN  325
#define KP   328     // EIN padded to multiple of 4
#define TE   16      // edges per block
#define TN   16      // nodes per block

__device__ __forceinline__ float silu_f(float x) {
    return x / (1.0f + __expf(-x));
}

// ---------------- tiny kernels ----------------
__global__ void k_latip(const float* __restrict__ lat, float* __restrict__ latip, int G) {
    int idx = blockIdx.x * 256 + threadIdx.x;
    if (idx >= G * 9) return;
    int g = idx / 9, ij = idx - g * 9, i = ij / 3, k = ij - (ij / 3) * 3;
    const float* L = lat + g * 9;
    latip[idx] = L[i*3+0]*L[k*3+0] + L[i*3+1]*L[k*3+1] + L[i*3+2]*L[k*3+2];
}

__global__ void k_deg(const int* __restrict__ ei1, float* __restrict__ degcnt, int E) {
    int idx = blockIdx.x * 256 + threadIdx.x;
    if (idx < E) atomicAdd(&degcnt[ei1[idx]], 1.0f);
}

__global__ void k_deginv(float* __restrict__ degcnt, int N) {
    int idx = blockIdx.x * 256 + threadIdx.x;
    if (idx < N) degcnt[idx] = 1.0f / fmaxf(degcnt[idx], 1.0f);
}

__global__ void k_fin(const float* __restrict__ outsum, const float* __restrict__ deginv,
                      float* __restrict__ out, int N) {
    int idx = blockIdx.x * 256 + threadIdx.x;
    if (idx < N * 3) out[idx] = outsum[idx] * deginv[idx / 3];
}

// ---------------- node init: h = [embed(atom), t_emb] @ lat_w + lat_b ----------------
__global__ __launch_bounds__(256) void k_init(
    const int* __restrict__ at, const float* __restrict__ t,
    const float* __restrict__ embed, const float* __restrict__ lat_w,
    const float* __restrict__ lat_b, float* __restrict__ h, int N)
{
    __shared__ float xs[TN * 384];
    __shared__ float Wc[64 * HD];
    int tid = threadIdx.x;
    int n0  = blockIdx.x * TN;

    for (int idx = tid; idx < TN * 384; idx += 256) {
        int r = idx / 384, c = idx - r * 384;
        int n = n0 + r;
        float v = 0.f;
        if (n < N) {
            if (c < HD) {
                v = embed[(at[n] - 1) * HD + c];
            } else if (c < 256) {
                float fr = __expf(-(float)(c - 128) * 0.07252236514f); // ln(1e4)/127
                v = __sinf(t[n] * fr);
            } else {
                float fr = __expf(-(float)(c - 256) * 0.07252236514f);
                v = __cosf(t[n] * fr);
            }
        }
        xs[idx] = v;
    }

    int c0 = (tid & 63) * 2;
    int rg = tid >> 6;
    float acc[4][2] = {};
    for (int kc = 0; kc < 384; kc += 64) {
        __syncthreads();
        for (int i = tid; i < (64 * HD) >> 2; i += 256) {
            int elem = i << 2;
            *(float4*)&Wc[elem] = *(const float4*)(lat_w + kc * HD + elem);
        }
        __syncthreads();
        for (int kk = 0; kk < 64; kk += 4) {
            float xr[4][4];
            #pragma unroll
            for (int j = 0; j < 4; ++j)
                *(float4*)xr[j] = *(const float4*)&xs[(rg*4 + j) * 384 + kc + kk];
            #pragma unroll
            for (int q = 0; q < 4; ++q) {
                float2 w = *(const float2*)&Wc[(kk + q) * HD + c0];
                #pragma unroll
                for (int j = 0; j < 4; ++j) {
                    acc[j][0] = fmaf(xr[j][q], w.x, acc[j][0]);
                    acc[j][1] = fmaf(xr[j][q], w.y, acc[j][1]);
                }
            }
        }
    }
    float b0 = lat_b[c0], b1v = lat_b[c0 + 1];
    #pragma unroll
    for (int j = 0; j < 4; ++j) {
        int n = n0 + rg * 4 + j;
        if (n < N) {
            h[n * HD + c0]     = acc[j][0] + b0;
            h[n * HD + c0 + 1] = acc[j][1] + b1v;
        }
    }
}

// ---------------- fused edge kernel (per layer) ----------------
// builds hij in LDS, runs silu(silu(hij@W1+b1)@W2+b2); non-last: atomic scatter into aggsum;
// last: fused gate = silu(ef@cw1+cb1)@cw2, atomic scatter frac_diff*gate into outsum.
template <bool LAST>
__global__ __launch_bounds__(256) void k_edge(
    const int* __restrict__ ei, const int* __restrict__ n2g,
    const float* __restrict__ fc, const float* __restrict__ latip,
    const float* __restrict__ h,
    const float* __restrict__ W1, const float* __restrict__ b1,
    const float* __restrict__ W2, const float* __restrict__ b2,
    const float* __restrict__ cw1, const float* __restrict__ cb1,
    const float* __restrict__ cw2,
    float* __restrict__ aggsum, float* __restrict__ outsum, int E)
{
    __shared__ float xs[TE * KP];    // 21.0 KB  hij tile (padded with zeros)
    __shared__ float Wc[64 * HD];    // 32.0 KB  weight chunk
    __shared__ float x1s[TE * HD];   //  8.0 KB  intermediate activations
    __shared__ int   ea[TE], eb[TE], eg[TE];
    __shared__ float fdl[TE][3];

    int tid = threadIdx.x;
    int e0  = blockIdx.x * TE;

    if (tid < TE) {
        int e = e0 + tid;
        if (e < E) {
            int a = ei[e], b = ei[E + e];
            ea[tid] = a; eb[tid] = b; eg[tid] = n2g[a];
            #pragma unroll
            for (int d = 0; d < 3; ++d) {
                float s = fc[b * 3 + d] - fc[a * 3 + d];
                fdl[tid][d] = s - floorf(s + 0.5f + 1e-4f);
            }
        } else {
            ea[tid] = 0; eb[tid] = -1; eg[tid] = 0;
            fdl[tid][0] = fdl[tid][1] = fdl[tid][2] = 0.f;
        }
    }
    __syncthreads();

    // stage hij = [h[a], h[b], latip[g], dis] ; dis[j] = sin/cos(fd[d] * 2pi*w)
    for (int idx = tid; idx < TE * EIN; idx += 256) {
        int r = idx / EIN, f = idx - r * EIN;
        float v;
        if (f < HD) {
            v = h[ea[r] * HD + f];
        } else if (f < 2 * HD) {
            int b = eb[r] < 0 ? 0 : eb[r];
            v = h[b * HD + (f - HD)];
        } else if (f < 2 * HD + 9) {
            v = latip[eg[r] * 9 + (f - 2 * HD)];
        } else {
            int j = f - (2 * HD + 9);
            bool is_sin = j < 30;
            int jj = is_sin ? j : j - 30;
            int d = jj / 10, w = jj - d * 10;
            float arg = fdl[r][d] * (6.283185307179586f * (float)w);
            v = is_sin ? __sinf(arg) : __cosf(arg);
        }
        xs[r * KP + f] = v;
    }
    if (tid < TE * 3) {                 // zero-pad k = 325..327
        int r = tid / 3;
        xs[r * KP + EIN + (tid - r * 3)] = 0.f;
    }

    int c0 = (tid & 63) * 2;
    int rg = tid >> 6;

    // ---- GEMM1: x1 = silu(hij @ W1 + b1), K = 328 (padded) ----
    float acc[4][2] = {};
    for (int kc = 0; kc < KP; kc += 64) {
        int kn = min(64, KP - kc);
        int valid = min(kn, EIN - kc);   // rows with real weights
        __syncthreads();
        int cnt4 = (kn * HD) >> 2;
        for (int i = tid; i < cnt4; i += 256) {
            int elem = i << 2;
            float4 v;
            if (elem < valid * HD) v = *(const float4*)(W1 + kc * HD + elem);
            else                   v = make_float4(0.f, 0.f, 0.f, 0.f);
            *(float4*)&Wc[elem] = v;
        }
        __syncthreads();
        for (int kk = 0; kk < kn; kk += 4) {
            float xr[4][4];
            #pragma unroll
            for (int j = 0; j < 4; ++j)
                *(float4*)xr[j] = *(const float4*)&xs[(rg*4 + j) * KP + kc + kk];
            #pragma unroll
            for (int q = 0; q < 4; ++q) {
                float2 w = *(const float2*)&Wc[(kk + q) * HD + c0];
                #pragma unroll
                for (int j = 0; j < 4; ++j) {
                    acc[j][0] = fmaf(xr[j][q], w.x, acc[j][0]);
                    acc[j][1] = fmaf(xr[j][q], w.y, acc[j][1]);
                }
            }
        }
    }
    {
        float bb0 = b1[c0], bb1 = b1[c0 + 1];
        #pragma unroll
        for (int j = 0; j < 4; ++j) {
            float2 v;
            v.x = silu_f(acc[j][0] + bb0);
            v.y = silu_f(acc[j][1] + bb1);
            *(float2*)&x1s[(rg*4 + j) * HD + c0] = v;
        }
    }

    // ---- GEMM2: ef = silu(x1 @ W2 + b2), K = 128 ----
    float acc2[4][2] = {};
    for (int kc = 0; kc < HD; kc += 64) {
        __syncthreads();
        for (int i = tid; i < (64 * HD) >> 2; i += 256) {
            int elem = i << 2;
            *(float4*)&Wc[elem] = *(const float4*)(W2 + kc * HD + elem);
        }
        __syncthreads();
        for (int kk = 0; kk < 64; kk += 4) {
            float xr[4][4];
            #pragma unroll
            for (int j = 0; j < 4; ++j)
                *(float4*)xr[j] = *(const float4*)&x1s[(rg*4 + j) * HD + kc + kk];
            #pragma unroll
            for (int q = 0; q < 4; ++q) {
                float2 w = *(const float2*)&Wc[(kk + q) * HD + c0];
                #pragma unroll
                for (int j = 0; j < 4; ++j) {
                    acc2[j][0] = fmaf(xr[j][q], w.x, acc2[j][0]);
                    acc2[j][1] = fmaf(xr[j][q], w.y, acc2[j][1]);
                }
            }
        }
    }
    float ef[4][2];
    {
        float bb0 = b2[c0], bb1 = b2[c0 + 1];
        #pragma unroll
        for (int j = 0; j < 4; ++j) {
            ef[j][0] = silu_f(acc2[j][0] + bb0);
            ef[j][1] = silu_f(acc2[j][1] + bb1);
        }
    }

    if (!LAST) {
        // scatter-add into aggsum (seg-sum by ei1)
        #pragma unroll
        for (int j = 0; j < 4; ++j) {
            int b = eb[rg * 4 + j];
            if (b >= 0) {
                atomicAdd(&aggsum[b * HD + c0],     ef[j][0]);
                atomicAdd(&aggsum[b * HD + c0 + 1], ef[j][1]);
            }
        }
    } else {
        // fused gate: gate = silu(ef @ cw1 + cb1) @ cw2 ; scatter fd*gate into outsum
        __syncthreads();                       // GEMM2 done reading x1s
        #pragma unroll
        for (int j = 0; j < 4; ++j)
            *(float2*)&x1s[(rg*4 + j) * HD + c0] = make_float2(ef[j][0], ef[j][1]);

        float acc3[4][2] = {};
        for (int kc = 0; kc < HD; kc += 64) {
            __syncthreads();
            for (int i = tid; i < (64 * HD) >> 2; i += 256) {
                int elem = i << 2;
                *(float4*)&Wc[elem] = *(const float4*)(cw1 + kc * HD + elem);
            }
            __syncthreads();
            for (int kk = 0; kk < 64; kk += 4) {
                float xr[4][4];
                #pragma unroll
                for (int j = 0; j < 4; ++j)
                    *(float4*)xr[j] = *(const float4*)&x1s[(rg*4 + j) * HD + kc + kk];
                #pragma unroll
                for (int q = 0; q < 4; ++q) {
                    float2 w = *(const float2*)&Wc[(kk + q) * HD + c0];
                    #pragma unroll
                    for (int j = 0; j < 4; ++j) {
                        acc3[j][0] = fmaf(xr[j][q], w.x, acc3[j][0]);
                        acc3[j][1] = fmaf(xr[j][q], w.y, acc3[j][1]);
                    }
                }
            }
        }
        float w20 = cw2[c0], w21 = cw2[c0 + 1];
        float cb0 = cb1[c0], cbv1 = cb1[c0 + 1];
        #pragma unroll
        for (int j = 0; j < 4; ++j) {
            float t0 = silu_f(acc3[j][0] + cb0);
            float t1 = silu_f(acc3[j][1] + cbv1);
            float p = fmaf(t0, w20, t1 * w21);
            p += __shfl_xor(p, 32);
            p += __shfl_xor(p, 16);
            p += __shfl_xor(p, 8);
            p += __shfl_xor(p, 4);
            p += __shfl_xor(p, 2);
            p += __shfl_xor(p, 1);
            if ((tid & 63) == 0) {
                int r = rg * 4 + j;
                int b = eb[r];
                if (b >= 0) {
                    atomicAdd(&outsum[b * 3 + 0], fdl[r][0] * p);
                    atomicAdd(&outsum[b * 3 + 1], fdl[r][1] * p);
                    atomicAdd(&outsum[b * 3 + 2], fdl[r][2] * p);
                }
            }
        }
    }
}

// ---------------- node update kernel (per layer) ----------------
// h += silu(silu([h, agg] @ nw1 + nb1) @ nw2 + nb2); also zeroes aggsum for next layer.
__global__ __launch_bounds__(256) void k_node(
    float* __restrict__ h, float* __restrict__ aggsum,
    const float* __restrict__ deginv,
    const float* __restrict__ W1, const float* __restrict__ b1,
    const float* __restrict__ W2, const float* __restrict__ b2, int N)
{
    __shared__ float xs[TN * 256];
    __shared__ float Wc[64 * HD];
    __shared__ float y1s[TN * HD];
    int tid = threadIdx.x;
    int n0  = blockIdx.x * TN;

    for (int idx = tid; idx < TN * 256; idx += 256) {
        int r = idx >> 8, c = idx & 255;
        int n = n0 + r;
        float v = 0.f;
        if (n < N) {
            if (c < HD) {
                v = h[n * HD + c];
            } else {
                v = aggsum[n * HD + (c - HD)] * deginv[n];
                aggsum[n * HD + (c - HD)] = 0.f;   // ready for next layer
            }
        }
        xs[idx] = v;
    }

    int c0 = (tid & 63) * 2;
    int rg = tid >> 6;
    float acc[4][2] = {};
    for (int kc = 0; kc < 256; kc += 64) {
        __syncthreads();
        for (int i = tid; i < (64 * HD) >> 2; i += 256) {
            int elem = i << 2;
            *(float4*)&Wc[elem] = *(const float4*)(W1 + kc * HD + elem);
        }
        __syncthreads();
        for (int kk = 0; kk < 64; kk += 4) {
            float xr[4][4];
            #pragma unroll
            for (int j = 0; j < 4; ++j)
                *(float4*)xr[j] = *(const float4*)&xs[(rg*4 + j) * 256 + kc + kk];
            #pragma unroll
            for (int q = 0; q < 4; ++q) {
                float2 w = *(const float2*)&Wc[(kk + q) * HD + c0];
                #pragma unroll
                for (int j = 0; j < 4; ++j) {
                    acc[j][0] = fmaf(xr[j][q], w.x, acc[j][0]);
                    acc[j][1] = fmaf(xr[j][q], w.y, acc[j][1]);
                }
            }
        }
    }
    {
        float bb0 = b1[c0], bb1 = b1[c0 + 1];
        #pragma unroll
        for (int j = 0; j < 4; ++j) {
            float2 v;
            v.x = silu_f(acc[j][0] + bb0);
            v.y = silu_f(acc[j][1] + bb1);
            *(float2*)&y1s[(rg*4 + j) * HD + c0] = v;
        }
    }

    float acc2[4][2] = {};
    for (int kc = 0; kc < HD; kc += 64) {
        __syncthreads();
        for (int i = tid; i < (64 * HD) >> 2; i += 256) {
            int elem = i << 2;
            *(float4*)&Wc[elem] = *(const float4*)(W2 + kc * HD + elem);
        }
        __syncthreads();
        for (int kk = 0; kk < 64; kk += 4) {
            float xr[4][4];
            #pragma unroll
            for (int j = 0; j < 4; ++j)
                *(float4*)xr[j] = *(const float4*)&y1s[(rg*4 + j) * HD + kc + kk];
            #pragma unroll
            for (int q = 0; q < 4; ++q) {
                float2 w = *(const float2*)&Wc[(kk + q) * HD + c0];
                #pragma unroll
                for (int j = 0; j < 4; ++j) {
                    acc2[j][0] = fmaf(xr[j][q], w.x, acc2[j][0]);
                    acc2[j][1] = fmaf(xr[j][q], w.y, acc2[j][1]);
                }
            }
        }
    }
    {
        float bb0 = b2[c0], bb1 = b2[c0 + 1];
        #pragma unroll
        for (int j = 0; j < 4; ++j) {
            int n = n0 + rg * 4 + j;
            if (n < N) {
                h[n * HD + c0]     += silu_f(acc2[j][0] + bb0);
                h[n * HD + c0 + 1] += silu_f(acc2[j][1] + bb1);
            }
        }
    }
}

// ---------------- launcher ----------------
extern "C" void kernel_launch(void* const* d_in, const int* in_sizes, int n_in,
                              void* d_out, int out_size, void* d_ws, size_t ws_size,
                              hipStream_t stream)
{
    const int*   at    = (const int*)  d_in[0];
    const float* t     = (const float*)d_in[1];
    const float* fc    = (const float*)d_in[2];
    const int*   ei    = (const int*)  d_in[3];
    const float* lat   = (const float*)d_in[4];
    const int*   n2g   = (const int*)  d_in[5];
    const float* embed = (const float*)d_in[6];
    const float* lat_w = (const float*)d_in[7];
    const float* lat_b = (const float*)d_in[8];
    const float* ew1   = (const float*)d_in[9];
    const float* eb1   = (const float*)d_in[10];
    const float* ew2   = (const float*)d_in[11];
    const float* eb2   = (const float*)d_in[12];
    const float* nw1   = (const float*)d_in[13];
    const float* nb1   = (const float*)d_in[14];
    const float* nw2   = (const float*)d_in[15];
    const float* nb2   = (const float*)d_in[16];
    const float* cw1   = (const float*)d_in[17];
    const float* cb1   = (const float*)d_in[18];
    const float* cw2   = (const float*)d_in[19];

    int N = in_sizes[0];
    int E = in_sizes[3] / 2;
    int G = in_sizes[4] / 9;

    float* ws     = (float*)d_ws;
    float* h      = ws;
    float* aggsum = h + (size_t)N * HD;
    float* outsum = aggsum + (size_t)N * HD;
    float* degbuf = outsum + (size_t)N * 3;
    float* latip  = degbuf + N;

    // zero aggsum + outsum + degbuf (contiguous)
    hipMemsetAsync(aggsum, 0, ((size_t)N * HD + (size_t)N * 3 + N) * sizeof(float), stream);

    k_latip <<<(G * 9 + 255) / 256, 256, 0, stream>>>(lat, latip, G);
    k_deg   <<<(E + 255) / 256,     256, 0, stream>>>(ei + E, degbuf, E);
    k_deginv<<<(N + 255) / 256,     256, 0, stream>>>(degbuf, N);
    k_init  <<<(N + TN - 1) / TN,   256, 0, stream>>>(at, t, embed, lat_w, lat_b, h, N);

    int eblocks = (E + TE - 1) / TE;
    int nblocks = (N + TN - 1) / TN;
    for (int l = 0; l < 3; ++l) {
        k_edge<false><<<eblocks, 256, 0, stream>>>(ei, n2g, fc, latip, h,
            ew1 + (size_t)l * EIN * HD, eb1 + l * HD,
            ew2 + (size_t)l * HD * HD,  eb2 + l * HD,
            cw1, cb1, cw2, aggsum, outsum, E);
        k_node<<<nblocks, 256, 0, stream>>>(h, aggsum, degbuf,
            nw1 + (size_t)l * 2 * HD * HD, nb1 + l * HD,
            nw2 + (size_t)l * HD * HD,     nb2 + l * HD, N);
    }
    // layer 3: node update is dead code (h unused afterwards); fuse gate + output scatter
    k_edge<true><<<eblocks, 256, 0, stream>>>(ei, n2g, fc, latip, h,
        ew1 + (size_t)3 * EIN * HD, eb1 + 3 * HD,
        ew2 + (size_t)3 * HD * HD,  eb2 + 3 * HD,
        cw1, cb1, cw2, aggsum, outsum, E);

    k_fin<<<(N * 3 + 255) / 256, 256, 0, stream>>>(outsum, degbuf, (float*)d_out, N);
}

// Round 2
// 930.482 us; speedup vs baseline: 16.4331x; 16.4331x over previous
//
#include <hip/hip_runtime.h>
#include <hip/hip_bf16.h>
#include <hip/hip_fp16.h>
#include <math.h>

#define HD    128
#define EIN   325
#define KP1   336      // GEMM1 K padded to 21*16
#define AST   344      // edge A-tile row stride (f16), 336+8 (bank stagger)
#define XST   136      // x1 tile row stride (f16)
#define RST   132      // fp32 reduce buffer row stride
#define NST   264      // node A-tile row stride (f16), 256+8

typedef _Float16 half8 __attribute__((ext_vector_type(8)));
typedef float    floatx16 __attribute__((ext_vector_type(16)));

__device__ __forceinline__ float silu_f(float x) {
    return x / (1.0f + __expf(-x));
}

// ---------------- weight prep: fp32 [m][K][N] -> fp16 [m][N][Kpad] (transposed) ----
__global__ void k_wprep(const float* __restrict__ src, _Float16* __restrict__ dst,
                        int K, int N, int Kpad, int nmat) {
    int idx = blockIdx.x * 256 + threadIdx.x;
    int per = N * Kpad;
    if (idx >= nmat * per) return;
    int m = idx / per, r = idx - m * per;
    int n = r / Kpad, k = r - n * Kpad;
    float v = (k < K) ? src[(size_t)m * K * N + (size_t)k * N + n] : 0.f;
    dst[idx] = (_Float16)v;
}

// ---------------- tiny kernels ----------------
__global__ void k_latip(const float* __restrict__ lat, float* __restrict__ latip, int G) {
    int idx = blockIdx.x * 256 + threadIdx.x;
    if (idx >= G * 9) return;
    int g = idx / 9, ij = idx - g * 9, i = ij / 3, k = ij - (ij / 3) * 3;
    const float* L = lat + g * 9;
    latip[idx] = L[i*3+0]*L[k*3+0] + L[i*3+1]*L[k*3+1] + L[i*3+2]*L[k*3+2];
}

__global__ void k_hist(const int* __restrict__ ei1, int* __restrict__ cnt, int E) {
    int idx = blockIdx.x * 256 + threadIdx.x;
    if (idx < E) atomicAdd(&cnt[ei1[idx]], 1);
}

__global__ void k_deginv(const int* __restrict__ cnt, float* __restrict__ deginv, int N) {
    int idx = blockIdx.x * 256 + threadIdx.x;
    if (idx < N) deginv[idx] = 1.0f / fmaxf((float)cnt[idx], 1.0f);
}

// single-block exclusive scan: head[i] = sum_{j<i} cnt[j]
__global__ __launch_bounds__(1024) void k_scan(const int* __restrict__ cnt,
                                               int* __restrict__ head, int N) {
    __shared__ int part[1024];
    int tid = threadIdx.x;
    int chunk = (N + 1023) >> 10;
    int start = tid * chunk, stop = min(start + chunk, N);
    int s = 0;
    for (int i = start; i < stop; ++i) s += cnt[i];
    part[tid] = s;
    __syncthreads();
    for (int off = 1; off < 1024; off <<= 1) {
        int v = (tid >= off) ? part[tid - off] : 0;
        __syncthreads();
        part[tid] += v;
        __syncthreads();
    }
    int run = (tid > 0) ? part[tid - 1] : 0;
    for (int i = start; i < stop; ++i) { head[i] = run; run += cnt[i]; }
}

__global__ void k_scatter(const int* __restrict__ ei1, int* __restrict__ head,
                          int* __restrict__ perm, int E) {
    int e = blockIdx.x * 256 + threadIdx.x;
    if (e < E) {
        int d = ei1[e];
        int pos = atomicAdd(&head[d], 1);
        perm[pos] = e;
    }
}

__global__ void k_fin(const float* __restrict__ outsum, const float* __restrict__ deginv,
                      float* __restrict__ out, int N) {
    int idx = blockIdx.x * 256 + threadIdx.x;
    if (idx < N * 3) out[idx] = outsum[idx] * deginv[idx / 3];
}

// ---------------- node init: h = [embed(atom), t_emb] @ lat_w + lat_b (fp32 VALU) ----
#define TN 16
__global__ __launch_bounds__(256) void k_init(
    const int* __restrict__ at, const float* __restrict__ t,
    const float* __restrict__ embed, const float* __restrict__ lat_w,
    const float* __restrict__ lat_b, float* __restrict__ h,
    _Float16* __restrict__ h16, int N)
{
    __shared__ float xs[TN * 384];
    __shared__ float Wc[64 * HD];
    int tid = threadIdx.x;
    int n0  = blockIdx.x * TN;

    for (int idx = tid; idx < TN * 384; idx += 256) {
        int r = idx / 384, c = idx - r * 384;
        int n = n0 + r;
        float v = 0.f;
        if (n < N) {
            if (c < HD) {
                v = embed[(at[n] - 1) * HD + c];
            } else if (c < 256) {
                float fr = __expf(-(float)(c - 128) * 0.07252236514f);
                v = __sinf(t[n] * fr);
            } else {
                float fr = __expf(-(float)(c - 256) * 0.07252236514f);
                v = __cosf(t[n] * fr);
            }
        }
        xs[idx] = v;
    }

    int c0 = (tid & 63) * 2;
    int rg = tid >> 6;
    float acc[4][2] = {};
    for (int kc = 0; kc < 384; kc += 64) {
        __syncthreads();
        for (int i = tid; i < (64 * HD) >> 2; i += 256) {
            int elem = i << 2;
            *(float4*)&Wc[elem] = *(const float4*)(lat_w + kc * HD + elem);
        }
        __syncthreads();
        for (int kk = 0; kk < 64; kk += 4) {
            float xr[4][4];
            #pragma unroll
            for (int j = 0; j < 4; ++j)
                *(float4*)xr[j] = *(const float4*)&xs[(rg*4 + j) * 384 + kc + kk];
            #pragma unroll
            for (int q = 0; q < 4; ++q) {
                float2 w = *(const float2*)&Wc[(kk + q) * HD + c0];
                #pragma unroll
                for (int j = 0; j < 4; ++j) {
                    acc[j][0] = fmaf(xr[j][q], w.x, acc[j][0]);
                    acc[j][1] = fmaf(xr[j][q], w.y, acc[j][1]);
                }
            }
        }
    }
    float b0 = lat_b[c0], b1v = lat_b[c0 + 1];
    #pragma unroll
    for (int j = 0; j < 4; ++j) {
        int n = n0 + rg * 4 + j;
        if (n < N) {
            float v0 = acc[j][0] + b0, v1 = acc[j][1] + b1v;
            h[n * HD + c0]     = v0;
            h[n * HD + c0 + 1] = v1;
            h16[n * HD + c0]     = (_Float16)v0;
            h16[n * HD + c0 + 1] = (_Float16)v1;
        }
    }
}

// ---------------- fused MFMA edge kernel (per layer) ----------------
// 64 sorted edges/block. hij staged fp16 in LDS; 2x GEMM via mfma_32x32x16_f16.
// non-last: run-reduced scatter into aggsum. last: fused gate + output scatter.
template <bool LAST>
__global__ __launch_bounds__(256) void k_edge(
    const int* __restrict__ ei, const int* __restrict__ n2g,
    const float* __restrict__ fc, const float* __restrict__ latip,
    const _Float16* __restrict__ h16, const int* __restrict__ perm,
    const _Float16* __restrict__ W1T, const float* __restrict__ b1,
    const _Float16* __restrict__ W2T, const float* __restrict__ b2,
    const _Float16* __restrict__ cw1T, const float* __restrict__ cb1,
    const float* __restrict__ cw2,
    float* __restrict__ aggsum, float* __restrict__ outsum, int E)
{
    __shared__ __align__(16) _Float16 xs[64 * AST];   // 43 KB; aliased below
    __shared__ int   ebL[64], egL[64], eaL[64];
    __shared__ float fdlL[64][3];
    __shared__ float gateL[64];
    _Float16* x1s = xs;                                // fp16 x1 / ef tile (after GEMM1)
    float*    red = (float*)xs;                        // fp32 reduce buffer (after GEMM2)

    int tid = threadIdx.x;
    int s0  = blockIdx.x * 64;

    if (tid < 64) {
        int s = s0 + tid;
        if (s < E) {
            int e = perm[s];
            int a = ei[e], b = ei[E + e];
            eaL[tid] = a; ebL[tid] = b; egL[tid] = n2g[a];
            #pragma unroll
            for (int d = 0; d < 3; ++d) {
                float sh = fc[b * 3 + d] - fc[a * 3 + d];
                fdlL[tid][d] = sh - floorf(sh + 0.5f + 1e-4f);
            }
        } else {
            eaL[tid] = 0; ebL[tid] = -1; egL[tid] = 0;
            fdlL[tid][0] = fdlL[tid][1] = fdlL[tid][2] = 0.f;
        }
        gateL[tid] = 0.f;
    }
    __syncthreads();

    // stage hij: [h[a] | h[b] | latip | dis | pad]
    for (int c = tid; c < 64 * 16; c += 256) {           // h[a], 16B chunks
        int row = c >> 4, p = c & 15;
        *(uint4*)(xs + row * AST + p * 8) =
            *(const uint4*)(h16 + (size_t)eaL[row] * HD + p * 8);
    }
    for (int c = tid; c < 64 * 16; c += 256) {           // h[b]
        int row = c >> 4, p = c & 15;
        int b = ebL[row] < 0 ? 0 : ebL[row];
        *(uint4*)(xs + row * AST + HD + p * 8) =
            *(const uint4*)(h16 + (size_t)b * HD + p * 8);
    }
    for (int c = tid; c < 64 * 9; c += 256) {            // latip
        int row = c / 9, j = c - row * 9;
        xs[row * AST + 256 + j] = (_Float16)latip[egL[row] * 9 + j];
    }
    for (int c = tid; c < 64 * 60; c += 256) {           // dis
        int row = c / 60, j = c - row * 60;
        bool is_sin = j < 30;
        int jj = is_sin ? j : j - 30;
        int d = jj / 10, w = jj - d * 10;
        float arg = fdlL[row][d] * (6.283185307179586f * (float)w);
        xs[row * AST + 265 + j] = (_Float16)(is_sin ? __sinf(arg) : __cosf(arg));
    }
    for (int c = tid; c < 64 * 11; c += 256) {           // zero-pad k=325..335
        int row = c / 11, j = c - row * 11;
        xs[row * AST + 325 + j] = (_Float16)0.f;
    }
    __syncthreads();

    int lane = tid & 63, w = tid >> 6;
    int l31 = lane & 31, lh = lane >> 5;
    int rm = (w >> 1) * 32;        // row-tile base
    int cb = (w & 1) * 64;         // col base; wave covers cols cb..cb+63
    int n0c = cb + l31, n1c = cb + 32 + l31;

    // ---- GEMM1: x1 = silu(hij @ W1 + b1), K = 336 ----
    floatx16 acc0 = {}, acc1 = {};
    {
        const _Float16* ap  = xs  + (size_t)(rm + l31) * AST + lh * 8;
        const _Float16* bp0 = W1T + (size_t)n0c * KP1 + lh * 8;
        const _Float16* bp1 = W1T + (size_t)n1c * KP1 + lh * 8;
        for (int ks = 0; ks < 21; ++ks) {
            half8 a  = *(const half8*)(ap  + ks * 16);
            half8 b0 = *(const half8*)(bp0 + ks * 16);
            half8 bb = *(const half8*)(bp1 + ks * 16);
            acc0 = __builtin_amdgcn_mfma_f32_32x32x16_f16(a, b0, acc0, 0, 0, 0);
            acc1 = __builtin_amdgcn_mfma_f32_32x32x16_f16(a, bb, acc1, 0, 0, 0);
        }
    }
    __syncthreads();               // everyone done reading xs
    {
        float b10 = b1[n0c], b11 = b1[n1c];
        #pragma unroll
        for (int r = 0; r < 16; ++r) {
            int row = rm + (r & 3) + 8 * (r >> 2) + 4 * lh;
            x1s[row * XST + n0c] = (_Float16)silu_f(acc0[r] + b10);
            x1s[row * XST + n1c] = (_Float16)silu_f(acc1[r] + b11);
        }
    }
    __syncthreads();

    // ---- GEMM2: ef = silu(x1 @ W2 + b2), K = 128 ----
    acc0 = {}; acc1 = {};
    {
        const _Float16* ap  = x1s + (size_t)(rm + l31) * XST + lh * 8;
        const _Float16* bp0 = W2T + (size_t)n0c * HD + lh * 8;
        const _Float16* bp1 = W2T + (size_t)n1c * HD + lh * 8;
        for (int ks = 0; ks < 8; ++ks) {
            half8 a  = *(const half8*)(ap  + ks * 16);
            half8 b0 = *(const half8*)(bp0 + ks * 16);
            half8 bb = *(const half8*)(bp1 + ks * 16);
            acc0 = __builtin_amdgcn_mfma_f32_32x32x16_f16(a, b0, acc0, 0, 0, 0);
            acc1 = __builtin_amdgcn_mfma_f32_32x32x16_f16(a, bb, acc1, 0, 0, 0);
        }
    }
    __syncthreads();               // done reading x1s

    if (!LAST) {
        // silu + write fp32 tile, then run-reduced scatter (edges sorted by dest)
        {
            float b20 = b2[n0c], b21 = b2[n1c];
            #pragma unroll
            for (int r = 0; r < 16; ++r) {
                int row = rm + (r & 3) + 8 * (r >> 2) + 4 * lh;
                red[row * RST + n0c] = silu_f(acc0[r] + b20);
                red[row * RST + n1c] = silu_f(acc1[r] + b21);
            }
        }
        __syncthreads();
        int c2 = (tid & 63) * 2;
        int r0 = (tid >> 6) * 16;
        float sx = 0.f, sy = 0.f;
        int cur = -1;
        for (int r = r0; r < r0 + 16; ++r) {
            int d = ebL[r];
            float2 v = *(float2*)&red[r * RST + c2];
            if (d != cur) {
                if (cur >= 0) {
                    atomicAdd(&aggsum[(size_t)cur * HD + c2],     sx);
                    atomicAdd(&aggsum[(size_t)cur * HD + c2 + 1], sy);
                }
                cur = d; sx = v.x; sy = v.y;
            } else { sx += v.x; sy += v.y; }
        }
        if (cur >= 0) {
            atomicAdd(&aggsum[(size_t)cur * HD + c2],     sx);
            atomicAdd(&aggsum[(size_t)cur * HD + c2 + 1], sy);
        }
    } else {
        // ef (fp16) -> x1s, then GEMM3 vs cw1T, per-row dot with cw2
        {
            float b20 = b2[n0c], b21 = b2[n1c];
            #pragma unroll
            for (int r = 0; r < 16; ++r) {
                int row = rm + (r & 3) + 8 * (r >> 2) + 4 * lh;
                x1s[row * XST + n0c] = (_Float16)silu_f(acc0[r] + b20);
                x1s[row * XST + n1c] = (_Float16)silu_f(acc1[r] + b21);
            }
        }
        __syncthreads();
        acc0 = {}; acc1 = {};
        {
            const _Float16* ap  = x1s  + (size_t)(rm + l31) * XST + lh * 8;
            const _Float16* bp0 = cw1T + (size_t)n0c * HD + lh * 8;
            const _Float16* bp1 = cw1T + (size_t)n1c * HD + lh * 8;
            for (int ks = 0; ks < 8; ++ks) {
                half8 a  = *(const half8*)(ap  + ks * 16);
                half8 b0 = *(const half8*)(bp0 + ks * 16);
                half8 bb = *(const half8*)(bp1 + ks * 16);
                acc0 = __builtin_amdgcn_mfma_f32_32x32x16_f16(a, b0, acc0, 0, 0, 0);
                acc1 = __builtin_amdgcn_mfma_f32_32x32x16_f16(a, bb, acc1, 0, 0, 0);
            }
        }
        float cb0 = cb1[n0c], cb1v = cb1[n1c];
        float w0 = cw2[n0c],  w1 = cw2[n1c];
        #pragma unroll
        for (int r = 0; r < 16; ++r) {
            float p = silu_f(acc0[r] + cb0) * w0 + silu_f(acc1[r] + cb1v) * w1;
            p += __shfl_xor(p, 16);
            p += __shfl_xor(p, 8);
            p += __shfl_xor(p, 4);
            p += __shfl_xor(p, 2);
            p += __shfl_xor(p, 1);
            if (l31 == 0) {
                int row = rm + (r & 3) + 8 * (r >> 2) + 4 * lh;
                atomicAdd(&gateL[row], p);
            }
        }
        __syncthreads();
        if (tid < 64) {
            int r = tid, d = ebL[r];
            if (d >= 0 && (r == 0 || ebL[r - 1] != d)) {
                float sx = 0.f, sy = 0.f, sz = 0.f;
                for (int q = r; q < 64 && ebL[q] == d; ++q) {
                    float g = gateL[q];
                    sx += fdlL[q][0] * g; sy += fdlL[q][1] * g; sz += fdlL[q][2] * g;
                }
                atomicAdd(&outsum[d * 3 + 0], sx);
                atomicAdd(&outsum[d * 3 + 1], sy);
                atomicAdd(&outsum[d * 3 + 2], sz);
            }
        }
    }
}

// ---------------- MFMA node kernel (per layer) ----------------
// h += silu(silu([h, agg/deg] @ nw1 + b1) @ nw2 + b2); zeroes aggsum; refreshes h16.
__global__ __launch_bounds__(256) void k_node(
    float* __restrict__ h, _Float16* __restrict__ h16,
    float* __restrict__ aggsum, const float* __restrict__ deginv,
    const _Float16* __restrict__ W1T, const float* __restrict__ b1,
    const _Float16* __restrict__ W2T, const float* __restrict__ b2, int N)
{
    __shared__ __align__(16) _Float16 xs[64 * NST];   // 33 KB
    _Float16* x1s = xs;

    int tid = threadIdx.x;
    int n0  = blockIdx.x * 64;

    for (int c = tid; c < 64 * 16; c += 256) {          // h cols 0..127
        int row = c >> 4, p = c & 15;
        int node = n0 + row;
        uint4 v = {0, 0, 0, 0};
        if (node < N) v = *(const uint4*)(h16 + (size_t)node * HD + p * 8);
        *(uint4*)(xs + row * NST + p * 8) = v;
    }
    for (int c = tid; c < 64 * HD; c += 256) {          // agg cols 128..255 (+zero aggsum)
        int row = c >> 7, cc = c & 127;
        int node = n0 + row;
        float v = 0.f;
        if (node < N) {
            size_t gi = (size_t)node * HD + cc;
            v = aggsum[gi] * deginv[node];
            aggsum[gi] = 0.f;
        }
        xs[row * NST + HD + cc] = (_Float16)v;
    }
    __syncthreads();

    int lane = tid & 63, w = tid >> 6;
    int l31 = lane & 31, lh = lane >> 5;
    int rm = (w >> 1) * 32;
    int cbase = (w & 1) * 64;
    int n0c = cbase + l31, n1c = cbase + 32 + l31;

    floatx16 acc0 = {}, acc1 = {};
    {
        const _Float16* ap  = xs  + (size_t)(rm + l31) * NST + lh * 8;
        const _Float16* bp0 = W1T + (size_t)n0c * 256 + lh * 8;
        const _Float16* bp1 = W1T + (size_t)n1c * 256 + lh * 8;
        for (int ks = 0; ks < 16; ++ks) {
            half8 a  = *(const half8*)(ap  + ks * 16);
            half8 b0 = *(const half8*)(bp0 + ks * 16);
            half8 bb = *(const half8*)(bp1 + ks * 16);
            acc0 = __builtin_amdgcn_mfma_f32_32x32x16_f16(a, b0, acc0, 0, 0, 0);
            acc1 = __builtin_amdgcn_mfma_f32_32x32x16_f16(a, bb, acc1, 0, 0, 0);
        }
    }
    __syncthreads();
    {
        float b10 = b1[n0c], b11 = b1[n1c];
        #pragma unroll
        for (int r = 0; r < 16; ++r) {
            int row = rm + (r & 3) + 8 * (r >> 2) + 4 * lh;
            x1s[row * XST + n0c] = (_Float16)silu_f(acc0[r] + b10);
            x1s[row * XST + n1c] = (_Float16)silu_f(acc1[r] + b11);
        }
    }
    __syncthreads();

    acc0 = {}; acc1 = {};
    {
        const _Float16* ap  = x1s + (size_t)(rm + l31) * XST + lh * 8;
        const _Float16* bp0 = W2T + (size_t)n0c * HD + lh * 8;
        const _Float16* bp1 = W2T + (size_t)n1c * HD + lh * 8;
        for (int ks = 0; ks < 8; ++ks) {
            half8 a  = *(const half8*)(ap  + ks * 16);
            half8 b0 = *(const half8*)(bp0 + ks * 16);
            half8 bb = *(const half8*)(bp1 + ks * 16);
            acc0 = __builtin_amdgcn_mfma_f32_32x32x16_f16(a, b0, acc0, 0, 0, 0);
            acc1 = __builtin_amdgcn_mfma_f32_32x32x16_f16(a, bb, acc1, 0, 0, 0);
        }
    }
    {
        float b20 = b2[n0c], b21 = b2[n1c];
        #pragma unroll
        for (int r = 0; r < 16; ++r) {
            int row = rm + (r & 3) + 8 * (r >> 2) + 4 * lh;
            int node = n0 + row;
            if (node < N) {
                size_t g0 = (size_t)node * HD + n0c;
                size_t g1 = (size_t)node * HD + n1c;
                float v0 = h[g0] + silu_f(acc0[r] + b20);
                float v1 = h[g1] + silu_f(acc1[r] + b21);
                h[g0] = v0; h[g1] = v1;
                h16[g0] = (_Float16)v0; h16[g1] = (_Float16)v1;
            }
        }
    }
}

// ---------------- launcher ----------------
extern "C" void kernel_launch(void* const* d_in, const int* in_sizes, int n_in,
                              void* d_out, int out_size, void* d_ws, size_t ws_size,
                              hipStream_t stream)
{
    const int*   at    = (const int*)  d_in[0];
    const float* t     = (const float*)d_in[1];
    const float* fc    = (const float*)d_in[2];
    const int*   ei    = (const int*)  d_in[3];
    const float* lat   = (const float*)d_in[4];
    const int*   n2g   = (const int*)  d_in[5];
    const float* embed = (const float*)d_in[6];
    const float* lat_w = (const float*)d_in[7];
    const float* lat_b = (const float*)d_in[8];
    const float* ew1   = (const float*)d_in[9];
    const float* eb1   = (const float*)d_in[10];
    const float* ew2   = (const float*)d_in[11];
    const float* eb2   = (const float*)d_in[12];
    const float* nw1   = (const float*)d_in[13];
    const float* nb1   = (const float*)d_in[14];
    const float* nw2   = (const float*)d_in[15];
    const float* nb2   = (const float*)d_in[16];
    const float* cw1   = (const float*)d_in[17];
    const float* cb1   = (const float*)d_in[18];
    const float* cw2   = (const float*)d_in[19];

    int N = in_sizes[0];
    int E = in_sizes[3] / 2;
    int G = in_sizes[4] / 9;

    // ---- workspace carve ----
    char* p = (char*)d_ws;
    float* h      = (float*)p;  p += (size_t)N * HD * 4;
    float* aggsum = (float*)p;  p += (size_t)N * HD * 4;   // zeroed below
    float* outsum = (float*)p;  p += (size_t)N * 3 * 4;    // zeroed below
    int*   cnt    = (int*)p;    p += (size_t)N * 4;        // zeroed below
    int*   head   = (int*)p;    p += (size_t)N * 4;
    float* deginv = (float*)p;  p += (size_t)N * 4;
    float* latip  = (float*)p;  p += (size_t)G * 9 * 4;
    int*   perm   = (int*)p;    p += (size_t)E * 4;
    _Float16* h16  = (_Float16*)p; p += (size_t)N * HD * 2;
    _Float16* ew1T = (_Float16*)p; p += (size_t)4 * HD * KP1 * 2;
    _Float16* ew2T = (_Float16*)p; p += (size_t)4 * HD * HD * 2;
    _Float16* nw1T = (_Float16*)p; p += (size_t)3 * HD * 256 * 2;
    _Float16* nw2T = (_Float16*)p; p += (size_t)3 * HD * HD * 2;
    _Float16* cw1T = (_Float16*)p; p += (size_t)HD * HD * 2;

    // zero aggsum|outsum|cnt (contiguous)
    hipMemsetAsync(aggsum, 0, ((size_t)N * HD + (size_t)N * 3 + N) * 4, stream);

    // weight prep (fp16, transposed, K-padded)
    {
        int tot;
        tot = 4 * HD * KP1; k_wprep<<<(tot+255)/256, 256, 0, stream>>>(ew1, ew1T, EIN, HD, KP1, 4);
        tot = 4 * HD * HD;  k_wprep<<<(tot+255)/256, 256, 0, stream>>>(ew2, ew2T, HD, HD, HD, 4);
        tot = 3 * HD * 256; k_wprep<<<(tot+255)/256, 256, 0, stream>>>(nw1, nw1T, 256, HD, 256, 3);
        tot = 3 * HD * HD;  k_wprep<<<(tot+255)/256, 256, 0, stream>>>(nw2, nw2T, HD, HD, HD, 3);
        tot = 1 * HD * HD;  k_wprep<<<(tot+255)/256, 256, 0, stream>>>(cw1, cw1T, HD, HD, HD, 1);
    }

    k_latip  <<<(G * 9 + 255) / 256, 256, 0, stream>>>(lat, latip, G);
    k_hist   <<<(E + 255) / 256,     256, 0, stream>>>(ei + E, cnt, E);
    k_scan   <<<1, 1024, 0, stream>>>(cnt, head, N);
    k_deginv <<<(N + 255) / 256,     256, 0, stream>>>(cnt, deginv, N);
    k_scatter<<<(E + 255) / 256,     256, 0, stream>>>(ei + E, head, perm, E);
    k_init   <<<(N + TN - 1) / TN,   256, 0, stream>>>(at, t, embed, lat_w, lat_b, h, h16, N);

    int eblocks = (E + 63) / 64;
    int nblocks = (N + 63) / 64;
    for (int l = 0; l < 3; ++l) {
        k_edge<false><<<eblocks, 256, 0, stream>>>(ei, n2g, fc, latip, h16, perm,
            ew1T + (size_t)l * HD * KP1, eb1 + l * HD,
            ew2T + (size_t)l * HD * HD,  eb2 + l * HD,
            cw1T, cb1, cw2, aggsum, outsum, E);
        k_node<<<nblocks, 256, 0, stream>>>(h, h16, aggsum, deginv,
            nw1T + (size_t)l * HD * 256, nb1 + l * HD,
            nw2T + (size_t)l * HD * HD,  nb2 + l * HD, N);
    }
    k_edge<true><<<eblocks, 256, 0, stream>>>(ei, n2g, fc, latip, h16, perm,
        ew1T + (size_t)3 * HD * KP1, eb1 + 3 * HD,
        ew2T + (size_t)3 * HD * HD,  eb2 + 3 * HD,
        cw1T, cb1, cw2, aggsum, outsum, E);

    k_fin<<<(N * 3 + 255) / 256, 256, 0, stream>>>(outsum, deginv, (float*)d_out, N);
}

// Round 3
// 757.770 us; speedup vs baseline: 20.1786x; 1.2279x over previous
//
#include <hip/hip_runtime.h>
#include <hip/hip_bf16.h>
#include <hip/hip_fp16.h>
#include <math.h>

#define HD    128
#define EIN   325
#define PST   136      // pqr/x1/ef tile row stride (f16), 16B-aligned
#define DST   72       // dis tile row stride (f16)
#define NST   264      // node A-tile row stride (f16)
#define XST   136      // node x1 tile row stride
#define IST   408      // init A-tile row stride (400+8)

typedef _Float16 half8 __attribute__((ext_vector_type(8)));
typedef float    floatx16 __attribute__((ext_vector_type(16)));

__device__ __forceinline__ float silu_f(float x) {
    return x / (1.0f + __expf(-x));
}

// ---- generic weight prep: fp32 [m][Ktot][Nn] rows [krow0, krow0+Kact) -> fp16 [m][Nn][Kpad]
__global__ void k_wprep(const float* __restrict__ src, _Float16* __restrict__ dst,
                        int Ktot, int krow0, int Kact, int Nn, int Kpad, int nmat) {
    int idx = blockIdx.x * 256 + threadIdx.x;
    int per = Nn * Kpad;
    if (idx >= nmat * per) return;
    int m = idx / per, r = idx - m * per;
    int n = r / Kpad, k = r - n * Kpad;
    float v = (k < Kact) ? src[(size_t)m * Ktot * Nn + (size_t)(krow0 + k) * Nn + n] : 0.f;
    dst[idx] = (_Float16)v;
}

// ---- tiny kernels ----
__global__ void k_latip(const float* __restrict__ lat, float* __restrict__ latip, int G) {
    int idx = blockIdx.x * 256 + threadIdx.x;
    if (idx >= G * 9) return;
    int g = idx / 9, ij = idx - g * 9, i = ij / 3, k = ij - (ij / 3) * 3;
    const float* L = lat + g * 9;
    latip[idx] = L[i*3+0]*L[k*3+0] + L[i*3+1]*L[k*3+1] + L[i*3+2]*L[k*3+2];
}

__global__ void k_hist(const int* __restrict__ ei1, int* __restrict__ cnt, int E) {
    int idx = blockIdx.x * 256 + threadIdx.x;
    if (idx < E) atomicAdd(&cnt[ei1[idx]], 1);
}

__global__ void k_deginv(const int* __restrict__ cnt, float* __restrict__ deginv, int N) {
    int idx = blockIdx.x * 256 + threadIdx.x;
    if (idx < N) deginv[idx] = 1.0f / fmaxf((float)cnt[idx], 1.0f);
}

__global__ __launch_bounds__(1024) void k_scan(const int* __restrict__ cnt,
                                               int* __restrict__ head, int N) {
    __shared__ int part[1024];
    int tid = threadIdx.x;
    int chunk = (N + 1023) >> 10;
    int start = tid * chunk, stop = min(start + chunk, N);
    int s = 0;
    for (int i = start; i < stop; ++i) s += cnt[i];
    part[tid] = s;
    __syncthreads();
    for (int off = 1; off < 1024; off <<= 1) {
        int v = (tid >= off) ? part[tid - off] : 0;
        __syncthreads();
        part[tid] += v;
        __syncthreads();
    }
    int run = (tid > 0) ? part[tid - 1] : 0;
    for (int i = start; i < stop; ++i) { head[i] = run; run += cnt[i]; }
}

__global__ void k_scatter(const int* __restrict__ ei1, int* __restrict__ head,
                          int* __restrict__ perm, int E) {
    int e = blockIdx.x * 256 + threadIdx.x;
    if (e < E) {
        int d = ei1[e];
        int pos = atomicAdd(&head[d], 1);
        perm[pos] = e;
    }
}

// ---- sorted edge meta: a, b, g, frac_diff in sorted order ----
__global__ void k_esort(const int* __restrict__ ei, const int* __restrict__ n2g,
                        const float* __restrict__ fc, const int* __restrict__ perm,
                        int* __restrict__ eaS, int* __restrict__ ebS, int* __restrict__ egS,
                        float* __restrict__ fdS, int E) {
    int s = blockIdx.x * 256 + threadIdx.x;
    if (s >= E) return;
    int e = perm[s];
    int a = ei[e], b = ei[E + e];
    eaS[s] = a; ebS[s] = b; egS[s] = n2g[a];
    #pragma unroll
    for (int d = 0; d < 3; ++d) {
        float sh = fc[b * 3 + d] - fc[a * 3 + d];
        fdS[s * 3 + d] = sh - floorf(sh + 0.5f + 1e-4f);
    }
}

// ---- per-graph table: R[l][g][c] = latip[g] @ W1lat[l] + eb1[l] ----
__global__ void k_rlat(const float* __restrict__ latip, const float* __restrict__ ew1,
                       const float* __restrict__ eb1, _Float16* __restrict__ R16, int G) {
    int idx = blockIdx.x * 256 + threadIdx.x;
    if (idx >= 4 * G * HD) return;
    int l = idx / (G * HD), r = idx - l * (G * HD), g = r >> 7, c = r & 127;
    const float* W  = ew1 + (size_t)l * EIN * HD + 256 * HD;  // k-rows 256..264
    const float* lp = latip + g * 9;
    float s = eb1[l * HD + c];
    #pragma unroll
    for (int j = 0; j < 9; ++j) s = fmaf(lp[j], W[j * HD + c], s);
    R16[idx] = (_Float16)s;
}

__global__ void k_fin(const float* __restrict__ outsum, const float* __restrict__ deginv,
                      float* __restrict__ out, int N) {
    int idx = blockIdx.x * 256 + threadIdx.x;
    if (idx < N * 3) out[idx] = outsum[idx] * deginv[idx / 3];
}

// ---- node init (MFMA): h = [embed(atom), sin, cos] @ lat_w + lat_b ----
__global__ __launch_bounds__(256) void k_init(
    const int* __restrict__ at, const float* __restrict__ t,
    const float* __restrict__ embed, const _Float16* __restrict__ latwT,
    const float* __restrict__ lat_b, float* __restrict__ h,
    _Float16* __restrict__ h16, int N)
{
    __shared__ __align__(16) _Float16 xs[64 * IST];   // 51 KB
    __shared__ int   atL[64];
    __shared__ float tL[64];
    int tid = threadIdx.x;
    int n0  = blockIdx.x * 64;

    if (tid < 64) {
        int node = n0 + tid;
        atL[tid] = (node < N) ? at[node] - 1 : 0;
        tL[tid]  = (node < N) ? t[node] : 0.f;
    }
    __syncthreads();

    for (int c = tid; c < 64 * 32; c += 256) {       // embed cols 0..127
        int row = c >> 5, p = c & 31;
        float4 v = {0, 0, 0, 0};
        if (n0 + row < N) v = *(const float4*)(embed + (size_t)atL[row] * HD + p * 4);
        _Float16* d = xs + row * IST + p * 4;
        d[0] = (_Float16)v.x; d[1] = (_Float16)v.y; d[2] = (_Float16)v.z; d[3] = (_Float16)v.w;
    }
    for (int c = tid; c < 64 * 272; c += 256) {      // sin/cos cols 128..383 + pad
        int row = c / 272, j = c - row * 272;
        float v = 0.f;
        if (j < 256 && n0 + row < N) {
            int k = j & 127;
            float fr = __expf(-(float)k * 0.07252236514f);
            float a = tL[row] * fr;
            v = (j < 128) ? __sinf(a) : __cosf(a);
        }
        xs[row * IST + 128 + j] = (_Float16)v;
    }
    __syncthreads();

    int lane = tid & 63, w = tid >> 6;
    int l31 = lane & 31, lh = lane >> 5;
    int rm = (w >> 1) * 32, cb = (w & 1) * 64;
    int n0c = cb + l31, n1c = cb + 32 + l31;

    floatx16 acc0 = {}, acc1 = {};
    {
        const _Float16* ap  = xs + (size_t)(rm + l31) * IST + lh * 8;
        const _Float16* bp0 = latwT + (size_t)n0c * 400 + lh * 8;
        const _Float16* bp1 = latwT + (size_t)n1c * 400 + lh * 8;
        for (int ks = 0; ks < 25; ++ks) {
            half8 a  = *(const half8*)(ap  + ks * 16);
            half8 b0 = *(const half8*)(bp0 + ks * 16);
            half8 bb = *(const half8*)(bp1 + ks * 16);
            acc0 = __builtin_amdgcn_mfma_f32_32x32x16_f16(a, b0, acc0, 0, 0, 0);
            acc1 = __builtin_amdgcn_mfma_f32_32x32x16_f16(a, bb, acc1, 0, 0, 0);
        }
    }
    float b0 = lat_b[n0c], b1v = lat_b[n1c];
    #pragma unroll
    for (int r = 0; r < 16; ++r) {
        int row = rm + (r & 3) + 8 * (r >> 2) + 4 * lh;
        int node = n0 + row;
        if (node < N) {
            float v0 = acc0[r] + b0, v1 = acc1[r] + b1v;
            h[(size_t)node * HD + n0c] = v0;
            h[(size_t)node * HD + n1c] = v1;
            h16[(size_t)node * HD + n0c] = (_Float16)v0;
            h16[(size_t)node * HD + n1c] = (_Float16)v1;
        }
    }
}

// ---- per-layer node-scale GEMM: P = h@W1a, Q = h@W1b ----
__global__ __launch_bounds__(256) void k_pq(
    const _Float16* __restrict__ h16,
    const _Float16* __restrict__ WaT, const _Float16* __restrict__ WbT,
    _Float16* __restrict__ P16, _Float16* __restrict__ Q16, int N)
{
    __shared__ __align__(16) _Float16 xs[64 * PST];
    int tid = threadIdx.x;
    int n0  = blockIdx.x * 64;

    for (int c = tid; c < 64 * 16; c += 256) {
        int row = c >> 4, p = c & 15;
        uint4 v = {0, 0, 0, 0};
        if (n0 + row < N) v = *(const uint4*)(h16 + (size_t)(n0 + row) * HD + p * 8);
        *(uint4*)(xs + row * PST + p * 8) = v;
    }
    __syncthreads();

    int lane = tid & 63, w = tid >> 6;
    int l31 = lane & 31, lh = lane >> 5;
    int rm = (w >> 1) * 32;
    const _Float16* BT  = (w & 1) ? WbT : WaT;
    _Float16*       OUT = (w & 1) ? Q16 : P16;

    floatx16 acc[4] = {};
    const _Float16* ap = xs + (size_t)(rm + l31) * PST + lh * 8;
    for (int ks = 0; ks < 8; ++ks) {
        half8 a = *(const half8*)(ap + ks * 16);
        #pragma unroll
        for (int i = 0; i < 4; ++i) {
            half8 b = *(const half8*)(BT + (size_t)(i * 32 + l31) * HD + ks * 16 + lh * 8);
            acc[i] = __builtin_amdgcn_mfma_f32_32x32x16_f16(a, b, acc[i], 0, 0, 0);
        }
    }
    #pragma unroll
    for (int r = 0; r < 16; ++r) {
        int row = rm + (r & 3) + 8 * (r >> 2) + 4 * lh;
        int node = n0 + row;
        if (node < N) {
            #pragma unroll
            for (int i = 0; i < 4; ++i)
                OUT[(size_t)node * HD + i * 32 + l31] = (_Float16)acc[i][r];
        }
    }
}

// ---- fused edge kernel: x1 = silu(P[a]+Q[b]+R[g] + dis@Wd); ef = silu(x1@W2+b2); scatter ----
template <bool LAST>
__global__ __launch_bounds__(256) void k_edge(
    const int* __restrict__ eaS, const int* __restrict__ ebS,
    const int* __restrict__ egS, const float* __restrict__ fdS,
    const _Float16* __restrict__ P16, const _Float16* __restrict__ Q16,
    const _Float16* __restrict__ R16, const _Float16* __restrict__ WdT,
    const _Float16* __restrict__ W2T, const float* __restrict__ b2,
    const _Float16* __restrict__ cw1T, const float* __restrict__ cb1,
    const float* __restrict__ cw2,
    float* __restrict__ aggsum, float* __restrict__ outsum, int E)
{
    __shared__ __align__(16) _Float16 xt[64 * PST];   // pqr -> x1 -> ef (17.4 KB)
    __shared__ __align__(16) _Float16 dt[64 * DST];   // dis tile (9.2 KB)
    __shared__ int   eaL[64], ebL[64], egL[64];
    __shared__ float fdlL[64][3];
    __shared__ float gateL[64];

    int tid = threadIdx.x;
    int s0  = blockIdx.x * 64;

    if (tid < 64) {
        int s = s0 + tid;
        if (s < E) {
            eaL[tid] = eaS[s]; ebL[tid] = ebS[s]; egL[tid] = egS[s];
            fdlL[tid][0] = fdS[s * 3];
            fdlL[tid][1] = fdS[s * 3 + 1];
            fdlL[tid][2] = fdS[s * 3 + 2];
        } else {
            eaL[tid] = 0; ebL[tid] = -1; egL[tid] = 0;
            fdlL[tid][0] = fdlL[tid][1] = fdlL[tid][2] = 0.f;
        }
        gateL[tid] = 0.f;
    }
    __syncthreads();

    // PQR tile: xt[row] = P[a] + Q[b] + R[g]   (vector fp16 adds)
    for (int c = tid; c < 64 * 16; c += 256) {
        int row = c >> 4, p = c & 15;
        int b = ebL[row] < 0 ? 0 : ebL[row];
        half8 pv = *(const half8*)(P16 + (size_t)eaL[row] * HD + p * 8);
        half8 qv = *(const half8*)(Q16 + (size_t)b * HD + p * 8);
        half8 rv = *(const half8*)(R16 + (size_t)egL[row] * HD + p * 8);
        half8 s = pv + qv + rv;
        *(half8*)(xt + row * PST + p * 8) = s;
    }
    // dis tile (60 real cols + 4 zero pad)
    for (int c = tid; c < 64 * 64; c += 256) {
        int row = c >> 6, j = c & 63;
        _Float16 v = (_Float16)0.f;
        if (j < 60) {
            bool is_sin = j < 30;
            int jj = is_sin ? j : j - 30;
            int d = jj / 10, wq = jj - d * 10;
            float arg = fdlL[row][d] * (6.283185307179586f * (float)wq);
            v = (_Float16)(is_sin ? __sinf(arg) : __cosf(arg));
        }
        dt[row * DST + j] = v;
    }
    __syncthreads();

    int lane = tid & 63, w = tid >> 6;
    int l31 = lane & 31, lh = lane >> 5;
    int rm = (w >> 1) * 32, cb = (w & 1) * 64;
    int n0c = cb + l31, n1c = cb + 32 + l31;

    // ---- dis GEMM: K = 64 ----
    floatx16 acc0 = {}, acc1 = {};
    {
        const _Float16* ap  = dt + (size_t)(rm + l31) * DST + lh * 8;
        const _Float16* bp0 = WdT + (size_t)n0c * 64 + lh * 8;
        const _Float16* bp1 = WdT + (size_t)n1c * 64 + lh * 8;
        for (int ks = 0; ks < 4; ++ks) {
            half8 a = *(const half8*)(ap + ks * 16);
            acc0 = __builtin_amdgcn_mfma_f32_32x32x16_f16(a, *(const half8*)(bp0 + ks * 16), acc0, 0, 0, 0);
            acc1 = __builtin_amdgcn_mfma_f32_32x32x16_f16(a, *(const half8*)(bp1 + ks * 16), acc1, 0, 0, 0);
        }
    }
    // x1 = silu(accD + PQR), in place (each lane owns its (row,col))
    #pragma unroll
    for (int r = 0; r < 16; ++r) {
        int row = rm + (r & 3) + 8 * (r >> 2) + 4 * lh;
        float v0 = acc0[r] + (float)xt[row * PST + n0c];
        float v1 = acc1[r] + (float)xt[row * PST + n1c];
        xt[row * PST + n0c] = (_Float16)silu_f(v0);
        xt[row * PST + n1c] = (_Float16)silu_f(v1);
    }
    __syncthreads();

    // ---- GEMM2: ef = silu(x1 @ W2 + b2), K = 128 ----
    acc0 = {}; acc1 = {};
    {
        const _Float16* ap  = xt + (size_t)(rm + l31) * PST + lh * 8;
        const _Float16* bp0 = W2T + (size_t)n0c * HD + lh * 8;
        const _Float16* bp1 = W2T + (size_t)n1c * HD + lh * 8;
        for (int ks = 0; ks < 8; ++ks) {
            half8 a = *(const half8*)(ap + ks * 16);
            acc0 = __builtin_amdgcn_mfma_f32_32x32x16_f16(a, *(const half8*)(bp0 + ks * 16), acc0, 0, 0, 0);
            acc1 = __builtin_amdgcn_mfma_f32_32x32x16_f16(a, *(const half8*)(bp1 + ks * 16), acc1, 0, 0, 0);
        }
    }
    __syncthreads();   // all waves done reading xt

    // ef -> xt in place (fp16)
    {
        float b20 = b2[n0c], b21 = b2[n1c];
        #pragma unroll
        for (int r = 0; r < 16; ++r) {
            int row = rm + (r & 3) + 8 * (r >> 2) + 4 * lh;
            xt[row * PST + n0c] = (_Float16)silu_f(acc0[r] + b20);
            xt[row * PST + n1c] = (_Float16)silu_f(acc1[r] + b21);
        }
    }
    __syncthreads();

    if (!LAST) {
        // run-reduced scatter (edges sorted by dest)
        int c2 = (tid & 63) * 2;
        int r0 = (tid >> 6) * 16;
        float sx = 0.f, sy = 0.f;
        int cur = -1;
        for (int r = r0; r < r0 + 16; ++r) {
            int d = ebL[r];
            float vx = (float)xt[r * PST + c2];
            float vy = (float)xt[r * PST + c2 + 1];
            if (d != cur) {
                if (cur >= 0) {
                    atomicAdd(&aggsum[(size_t)cur * HD + c2],     sx);
                    atomicAdd(&aggsum[(size_t)cur * HD + c2 + 1], sy);
                }
                cur = d; sx = vx; sy = vy;
            } else { sx += vx; sy += vy; }
        }
        if (cur >= 0) {
            atomicAdd(&aggsum[(size_t)cur * HD + c2],     sx);
            atomicAdd(&aggsum[(size_t)cur * HD + c2 + 1], sy);
        }
    } else {
        // GEMM3: g1 = silu(ef @ cw1 + cb1); gate = g1 @ cw2; scatter fd*gate
        acc0 = {}; acc1 = {};
        {
            const _Float16* ap  = xt + (size_t)(rm + l31) * PST + lh * 8;
            const _Float16* bp0 = cw1T + (size_t)n0c * HD + lh * 8;
            const _Float16* bp1 = cw1T + (size_t)n1c * HD + lh * 8;
            for (int ks = 0; ks < 8; ++ks) {
                half8 a = *(const half8*)(ap + ks * 16);
                acc0 = __builtin_amdgcn_mfma_f32_32x32x16_f16(a, *(const half8*)(bp0 + ks * 16), acc0, 0, 0, 0);
                acc1 = __builtin_amdgcn_mfma_f32_32x32x16_f16(a, *(const half8*)(bp1 + ks * 16), acc1, 0, 0, 0);
            }
        }
        float cb0 = cb1[n0c], cb1v = cb1[n1c];
        float w0 = cw2[n0c],  w1 = cw2[n1c];
        #pragma unroll
        for (int r = 0; r < 16; ++r) {
            float p = silu_f(acc0[r] + cb0) * w0 + silu_f(acc1[r] + cb1v) * w1;
            p += __shfl_xor(p, 16);
            p += __shfl_xor(p, 8);
            p += __shfl_xor(p, 4);
            p += __shfl_xor(p, 2);
            p += __shfl_xor(p, 1);
            if (l31 == 0) {
                int row = rm + (r & 3) + 8 * (r >> 2) + 4 * lh;
                atomicAdd(&gateL[row], p);
            }
        }
        __syncthreads();
        if (tid < 64) {
            int r = tid, d = ebL[r];
            if (d >= 0 && (r == 0 || ebL[r - 1] != d)) {
                float sx = 0.f, sy = 0.f, sz = 0.f;
                for (int q = r; q < 64 && ebL[q] == d; ++q) {
                    float g = gateL[q];
                    sx += fdlL[q][0] * g; sy += fdlL[q][1] * g; sz += fdlL[q][2] * g;
                }
                atomicAdd(&outsum[d * 3 + 0], sx);
                atomicAdd(&outsum[d * 3 + 1], sy);
                atomicAdd(&outsum[d * 3 + 2], sz);
            }
        }
    }
}

// ---- MFMA node kernel: h += MLP([h, agg/deg]); zeroes aggsum; refreshes h16 ----
__global__ __launch_bounds__(256) void k_node(
    float* __restrict__ h, _Float16* __restrict__ h16,
    float* __restrict__ aggsum, const float* __restrict__ deginv,
    const _Float16* __restrict__ W1T, const float* __restrict__ b1,
    const _Float16* __restrict__ W2T, const float* __restrict__ b2, int N)
{
    __shared__ __align__(16) _Float16 xs[64 * NST];
    _Float16* x1s = xs;

    int tid = threadIdx.x;
    int n0  = blockIdx.x * 64;

    for (int c = tid; c < 64 * 16; c += 256) {
        int row = c >> 4, p = c & 15;
        int node = n0 + row;
        uint4 v = {0, 0, 0, 0};
        if (node < N) v = *(const uint4*)(h16 + (size_t)node * HD + p * 8);
        *(uint4*)(xs + row * NST + p * 8) = v;
    }
    for (int c = tid; c < 64 * HD; c += 256) {
        int row = c >> 7, cc = c & 127;
        int node = n0 + row;
        float v = 0.f;
        if (node < N) {
            size_t gi = (size_t)node * HD + cc;
            v = aggsum[gi] * deginv[node];
            aggsum[gi] = 0.f;
        }
        xs[row * NST + HD + cc] = (_Float16)v;
    }
    __syncthreads();

    int lane = tid & 63, w = tid >> 6;
    int l31 = lane & 31, lh = lane >> 5;
    int rm = (w >> 1) * 32, cbase = (w & 1) * 64;
    int n0c = cbase + l31, n1c = cbase + 32 + l31;

    floatx16 acc0 = {}, acc1 = {};
    {
        const _Float16* ap  = xs  + (size_t)(rm + l31) * NST + lh * 8;
        const _Float16* bp0 = W1T + (size_t)n0c * 256 + lh * 8;
        const _Float16* bp1 = W1T + (size_t)n1c * 256 + lh * 8;
        for (int ks = 0; ks < 16; ++ks) {
            half8 a  = *(const half8*)(ap  + ks * 16);
            acc0 = __builtin_amdgcn_mfma_f32_32x32x16_f16(a, *(const half8*)(bp0 + ks * 16), acc0, 0, 0, 0);
            acc1 = __builtin_amdgcn_mfma_f32_32x32x16_f16(a, *(const half8*)(bp1 + ks * 16), acc1, 0, 0, 0);
        }
    }
    __syncthreads();
    {
        float b10 = b1[n0c], b11 = b1[n1c];
        #pragma unroll
        for (int r = 0; r < 16; ++r) {
            int row = rm + (r & 3) + 8 * (r >> 2) + 4 * lh;
            x1s[row * XST + n0c] = (_Float16)silu_f(acc0[r] + b10);
            x1s[row * XST + n1c] = (_Float16)silu_f(acc1[r] + b11);
        }
    }
    __syncthreads();

    acc0 = {}; acc1 = {};
    {
        const _Float16* ap  = x1s + (size_t)(rm + l31) * XST + lh * 8;
        const _Float16* bp0 = W2T + (size_t)n0c * HD + lh * 8;
        const _Float16* bp1 = W2T + (size_t)n1c * HD + lh * 8;
        for (int ks = 0; ks < 8; ++ks) {
            half8 a  = *(const half8*)(ap  + ks * 16);
            acc0 = __builtin_amdgcn_mfma_f32_32x32x16_f16(a, *(const half8*)(bp0 + ks * 16), acc0, 0, 0, 0);
            acc1 = __builtin_amdgcn_mfma_f32_32x32x16_f16(a, *(const half8*)(bp1 + ks * 16), acc1, 0, 0, 0);
        }
    }
    {
        float b20 = b2[n0c], b21 = b2[n1c];
        #pragma unroll
        for (int r = 0; r < 16; ++r) {
            int row = rm + (r & 3) + 8 * (r >> 2) + 4 * lh;
            int node = n0 + row;
            if (node < N) {
                size_t g0 = (size_t)node * HD + n0c;
                size_t g1 = (size_t)node * HD + n1c;
                float v0 = h[g0] + silu_f(acc0[r] + b20);
                float v1 = h[g1] + silu_f(acc1[r] + b21);
                h[g0] = v0; h[g1] = v1;
                h16[g0] = (_Float16)v0; h16[g1] = (_Float16)v1;
            }
        }
    }
}

// ---------------- launcher ----------------
extern "C" void kernel_launch(void* const* d_in, const int* in_sizes, int n_in,
                              void* d_out, int out_size, void* d_ws, size_t ws_size,
                              hipStream_t stream)
{
    const int*   at    = (const int*)  d_in[0];
    const float* t     = (const float*)d_in[1];
    const float* fc    = (const float*)d_in[2];
    const int*   ei    = (const int*)  d_in[3];
    const float* lat   = (const float*)d_in[4];
    const int*   n2g   = (const int*)  d_in[5];
    const float* embed = (const float*)d_in[6];
    const float* lat_w = (const float*)d_in[7];
    const float* lat_b = (const float*)d_in[8];
    const float* ew1   = (const float*)d_in[9];
    const float* eb1   = (const float*)d_in[10];
    const float* ew2   = (const float*)d_in[11];
    const float* eb2   = (const float*)d_in[12];
    const float* nw1   = (const float*)d_in[13];
    const float* nb1   = (const float*)d_in[14];
    const float* nw2   = (const float*)d_in[15];
    const float* nb2   = (const float*)d_in[16];
    const float* cw1   = (const float*)d_in[17];
    const float* cb1   = (const float*)d_in[18];
    const float* cw2   = (const float*)d_in[19];

    int N = in_sizes[0];
    int E = in_sizes[3] / 2;
    int G = in_sizes[4] / 9;

    // ---- workspace carve ----
    char* p = (char*)d_ws;
    float* h      = (float*)p;  p += (size_t)N * HD * 4;
    float* aggsum = (float*)p;  p += (size_t)N * HD * 4;   // zeroed below
    float* outsum = (float*)p;  p += (size_t)N * 3 * 4;    // zeroed below
    int*   cnt    = (int*)p;    p += (size_t)N * 4;        // zeroed below
    int*   head   = (int*)p;    p += (size_t)N * 4;
    float* deginv = (float*)p;  p += (size_t)N * 4;
    float* latip  = (float*)p;  p += (size_t)G * 9 * 4;
    int*   perm   = (int*)p;    p += (size_t)E * 4;
    int*   eaS    = (int*)p;    p += (size_t)E * 4;
    int*   ebS    = (int*)p;    p += (size_t)E * 4;
    int*   egS    = (int*)p;    p += (size_t)E * 4;
    float* fdS    = (float*)p;  p += (size_t)E * 3 * 4;
    _Float16* h16   = (_Float16*)p; p += (size_t)N * HD * 2;
    _Float16* P16   = (_Float16*)p; p += (size_t)N * HD * 2;
    _Float16* Q16   = (_Float16*)p; p += (size_t)N * HD * 2;
    _Float16* w1aT  = (_Float16*)p; p += (size_t)4 * HD * HD * 2;
    _Float16* w1bT  = (_Float16*)p; p += (size_t)4 * HD * HD * 2;
    _Float16* wdT   = (_Float16*)p; p += (size_t)4 * HD * 64 * 2;
    _Float16* w2T   = (_Float16*)p; p += (size_t)4 * HD * HD * 2;
    _Float16* nw1T  = (_Float16*)p; p += (size_t)3 * HD * 256 * 2;
    _Float16* nw2T  = (_Float16*)p; p += (size_t)3 * HD * HD * 2;
    _Float16* cw1T  = (_Float16*)p; p += (size_t)HD * HD * 2;
    _Float16* latwT = (_Float16*)p; p += (size_t)HD * 400 * 2;
    _Float16* R16   = (_Float16*)p; p += (size_t)4 * G * HD * 2;

    // zero aggsum|outsum|cnt (contiguous)
    hipMemsetAsync(aggsum, 0, ((size_t)N * HD + (size_t)N * 3 + N) * 4, stream);

    // weight prep (fp16, transposed, K-padded)
    {
        int tot;
        tot = 4 * HD * HD;  k_wprep<<<(tot+255)/256, 256, 0, stream>>>(ew1, w1aT, EIN, 0,   128, HD, HD, 4);
        tot = 4 * HD * HD;  k_wprep<<<(tot+255)/256, 256, 0, stream>>>(ew1, w1bT, EIN, 128, 128, HD, HD, 4);
        tot = 4 * HD * 64;  k_wprep<<<(tot+255)/256, 256, 0, stream>>>(ew1, wdT,  EIN, 265, 60,  HD, 64, 4);
        tot = 4 * HD * HD;  k_wprep<<<(tot+255)/256, 256, 0, stream>>>(ew2, w2T,  HD,  0,  128, HD, HD, 4);
        tot = 3 * HD * 256; k_wprep<<<(tot+255)/256, 256, 0, stream>>>(nw1, nw1T, 256, 0,  256, HD, 256, 3);
        tot = 3 * HD * HD;  k_wprep<<<(tot+255)/256, 256, 0, stream>>>(nw2, nw2T, HD,  0,  128, HD, HD, 3);
        tot = 1 * HD * HD;  k_wprep<<<(tot+255)/256, 256, 0, stream>>>(cw1, cw1T, HD,  0,  128, HD, HD, 1);
        tot = HD * 400;     k_wprep<<<(tot+255)/256, 256, 0, stream>>>(lat_w, latwT, 384, 0, 384, HD, 400, 1);
    }

    k_latip  <<<(G * 9 + 255) / 256, 256, 0, stream>>>(lat, latip, G);
    k_hist   <<<(E + 255) / 256,     256, 0, stream>>>(ei + E, cnt, E);
    k_scan   <<<1, 1024, 0, stream>>>(cnt, head, N);
    k_deginv <<<(N + 255) / 256,     256, 0, stream>>>(cnt, deginv, N);
    k_scatter<<<(E + 255) / 256,     256, 0, stream>>>(ei + E, head, perm, E);
    k_esort  <<<(E + 255) / 256,     256, 0, stream>>>(ei, n2g, fc, perm, eaS, ebS, egS, fdS, E);
    k_rlat   <<<(4 * G * HD + 255) / 256, 256, 0, stream>>>(latip, ew1, eb1, R16, G);
    k_init   <<<(N + 63) / 64, 256, 0, stream>>>(at, t, embed, latwT, lat_b, h, h16, N);
    k_pq     <<<(N + 63) / 64, 256, 0, stream>>>(h16, w1aT, w1bT, P16, Q16, N);

    int eblocks = (E + 63) / 64;
    int nblocks = (N + 63) / 64;
    for (int l = 0; l < 3; ++l) {
        k_edge<false><<<eblocks, 256, 0, stream>>>(eaS, ebS, egS, fdS, P16, Q16,
            R16 + (size_t)l * G * HD, wdT + (size_t)l * HD * 64,
            w2T + (size_t)l * HD * HD, eb2 + l * HD,
            cw1T, cb1, cw2, aggsum, outsum, E);
        k_node<<<nblocks, 256, 0, stream>>>(h, h16, aggsum, deginv,
            nw1T + (size_t)l * HD * 256, nb1 + l * HD,
            nw2T + (size_t)l * HD * HD,  nb2 + l * HD, N);
        k_pq  <<<(N + 63) / 64, 256, 0, stream>>>(h16,
            w1aT + (size_t)(l + 1) * HD * HD, w1bT + (size_t)(l + 1) * HD * HD,
            P16, Q16, N);
    }
    k_edge<true><<<eblocks, 256, 0, stream>>>(eaS, ebS, egS, fdS, P16, Q16,
        R16 + (size_t)3 * G * HD, wdT + (size_t)3 * HD * 64,
        w2T + (size_t)3 * HD * HD, eb2 + 3 * HD,
        cw1T, cb1, cw2, aggsum, outsum, E);

    k_fin<<<(N * 3 + 255) / 256, 256, 0, stream>>>(outsum, deginv, (float*)d_out, N);
}

// Round 4
// 712.118 us; speedup vs baseline: 21.4722x; 1.0641x over previous
//
#include <hip/hip_runtime.h>
#include <hip/hip_bf16.h>
#include <hip/hip_fp16.h>
#include <math.h>

#define HD    128
#define EIN   325
#define PST   136      // pqr/x1/ef tile row stride (f16), 16B-aligned
#define NST   264      // node A-tile row stride (f16)
#define XST   136      // node x1 tile row stride
#define IST   408      // init A-tile row stride (400+8)

typedef _Float16 half8 __attribute__((ext_vector_type(8)));
typedef float    floatx16 __attribute__((ext_vector_type(16)));

__device__ __forceinline__ float silu_f(float x) {
    return x / (1.0f + __expf(-x));
}

// ---- generic weight prep: fp32 [m][Ktot][Nn] rows [krow0, krow0+Kact) -> fp16 [m][Nn][Kpad]
__global__ void k_wprep(const float* __restrict__ src, _Float16* __restrict__ dst,
                        int Ktot, int krow0, int Kact, int Nn, int Kpad, int nmat) {
    int idx = blockIdx.x * 256 + threadIdx.x;
    int per = Nn * Kpad;
    if (idx >= nmat * per) return;
    int m = idx / per, r = idx - m * per;
    int n = r / Kpad, k = r - n * Kpad;
    float v = (k < Kact) ? src[(size_t)m * Ktot * Nn + (size_t)(krow0 + k) * Nn + n] : 0.f;
    dst[idx] = (_Float16)v;
}

// ---- tiny kernels ----
__global__ void k_latip(const float* __restrict__ lat, float* __restrict__ latip, int G) {
    int idx = blockIdx.x * 256 + threadIdx.x;
    if (idx >= G * 9) return;
    int g = idx / 9, ij = idx - g * 9, i = ij / 3, k = ij - (ij / 3) * 3;
    const float* L = lat + g * 9;
    latip[idx] = L[i*3+0]*L[k*3+0] + L[i*3+1]*L[k*3+1] + L[i*3+2]*L[k*3+2];
}

__global__ void k_hist(const int* __restrict__ ei1, int* __restrict__ cnt, int E) {
    int idx = blockIdx.x * 256 + threadIdx.x;
    if (idx < E) atomicAdd(&cnt[ei1[idx]], 1);
}

__global__ void k_deginv(const int* __restrict__ cnt, float* __restrict__ deginv, int N) {
    int idx = blockIdx.x * 256 + threadIdx.x;
    if (idx < N) deginv[idx] = 1.0f / fmaxf((float)cnt[idx], 1.0f);
}

__global__ __launch_bounds__(1024) void k_scan(const int* __restrict__ cnt,
                                               int* __restrict__ head, int N) {
    __shared__ int part[1024];
    int tid = threadIdx.x;
    int chunk = (N + 1023) >> 10;
    int start = tid * chunk, stop = min(start + chunk, N);
    int s = 0;
    for (int i = start; i < stop; ++i) s += cnt[i];
    part[tid] = s;
    __syncthreads();
    for (int off = 1; off < 1024; off <<= 1) {
        int v = (tid >= off) ? part[tid - off] : 0;
        __syncthreads();
        part[tid] += v;
        __syncthreads();
    }
    int run = (tid > 0) ? part[tid - 1] : 0;
    for (int i = start; i < stop; ++i) { head[i] = run; run += cnt[i]; }
}

__global__ void k_scatter(const int* __restrict__ ei1, int* __restrict__ head,
                          int* __restrict__ perm, int E) {
    int e = blockIdx.x * 256 + threadIdx.x;
    if (e < E) {
        int d = ei1[e];
        int pos = atomicAdd(&head[d], 1);
        perm[pos] = e;
    }
}

// ---- sorted edge meta ----
__global__ void k_esort(const int* __restrict__ ei, const int* __restrict__ n2g,
                        const float* __restrict__ fc, const int* __restrict__ perm,
                        int* __restrict__ eaS, int* __restrict__ ebS, int* __restrict__ egS,
                        float* __restrict__ fdS, int E) {
    int s = blockIdx.x * 256 + threadIdx.x;
    if (s >= E) return;
    int e = perm[s];
    int a = ei[e], b = ei[E + e];
    eaS[s] = a; ebS[s] = b; egS[s] = n2g[a];
    #pragma unroll
    for (int d = 0; d < 3; ++d) {
        float sh = fc[b * 3 + d] - fc[a * 3 + d];
        fdS[s * 3 + d] = sh - floorf(sh + 0.5f + 1e-4f);
    }
}

// ---- per-graph table: R[l][g][c] = latip[g] @ W1lat[l] + eb1[l] ----
__global__ void k_rlat(const float* __restrict__ latip, const float* __restrict__ ew1,
                       const float* __restrict__ eb1, _Float16* __restrict__ R16, int G) {
    int idx = blockIdx.x * 256 + threadIdx.x;
    if (idx >= 4 * G * HD) return;
    int l = idx / (G * HD), r = idx - l * (G * HD), g = r >> 7, c = r & 127;
    const float* W  = ew1 + (size_t)l * EIN * HD + 256 * HD;  // k-rows 256..264
    const float* lp = latip + g * 9;
    float s = eb1[l * HD + c];
    #pragma unroll
    for (int j = 0; j < 9; ++j) s = fmaf(lp[j], W[j * HD + c], s);
    R16[idx] = (_Float16)s;
}

__global__ void k_fin(const float* __restrict__ outsum, const float* __restrict__ deginv,
                      float* __restrict__ out, int N) {
    int idx = blockIdx.x * 256 + threadIdx.x;
    if (idx < N * 3) out[idx] = outsum[idx] * deginv[idx / 3];
}

// ---- node init fused with first P/Q: h = [embed, sin, cos]@lat_w + b; P=h@Wa, Q=h@Wb ----
__global__ __launch_bounds__(256) void k_init_pq(
    const int* __restrict__ at, const float* __restrict__ t,
    const float* __restrict__ embed, const _Float16* __restrict__ latwT,
    const float* __restrict__ lat_b, float* __restrict__ h,
    _Float16* __restrict__ h16,
    const _Float16* __restrict__ WaT, const _Float16* __restrict__ WbT,
    _Float16* __restrict__ P16, _Float16* __restrict__ Q16, int N)
{
    __shared__ __align__(16) _Float16 xs[64 * IST];   // 51 KB
    __shared__ int   atL[64];
    __shared__ float tL[64];
    int tid = threadIdx.x;
    int n0  = blockIdx.x * 64;

    if (tid < 64) {
        int node = n0 + tid;
        atL[tid] = (node < N) ? at[node] - 1 : 0;
        tL[tid]  = (node < N) ? t[node] : 0.f;
    }
    __syncthreads();

    for (int c = tid; c < 64 * 32; c += 256) {       // embed cols 0..127
        int row = c >> 5, p = c & 31;
        float4 v = {0, 0, 0, 0};
        if (n0 + row < N) v = *(const float4*)(embed + (size_t)atL[row] * HD + p * 4);
        _Float16* d = xs + row * IST + p * 4;
        d[0] = (_Float16)v.x; d[1] = (_Float16)v.y; d[2] = (_Float16)v.z; d[3] = (_Float16)v.w;
    }
    for (int c = tid; c < 64 * 272; c += 256) {      // sin/cos cols 128..383 + pad
        int row = c / 272, j = c - row * 272;
        float v = 0.f;
        if (j < 256 && n0 + row < N) {
            int k = j & 127;
            float fr = __expf(-(float)k * 0.07252236514f);
            float a = tL[row] * fr;
            v = (j < 128) ? __sinf(a) : __cosf(a);
        }
        xs[row * IST + 128 + j] = (_Float16)v;
    }
    __syncthreads();

    int lane = tid & 63, wv = tid >> 6;
    int l31 = lane & 31, lh = lane >> 5;
    int rm = (wv >> 1) * 32, cb = (wv & 1) * 64;
    int n0c = cb + l31, n1c = cb + 32 + l31;

    floatx16 acc0 = {}, acc1 = {};
    {
        const _Float16* ap  = xs + (size_t)(rm + l31) * IST + lh * 8;
        const _Float16* bp0 = latwT + (size_t)n0c * 400 + lh * 8;
        const _Float16* bp1 = latwT + (size_t)n1c * 400 + lh * 8;
        for (int ks = 0; ks < 25; ++ks) {
            half8 a  = *(const half8*)(ap  + ks * 16);
            acc0 = __builtin_amdgcn_mfma_f32_32x32x16_f16(a, *(const half8*)(bp0 + ks * 16), acc0, 0, 0, 0);
            acc1 = __builtin_amdgcn_mfma_f32_32x32x16_f16(a, *(const half8*)(bp1 + ks * 16), acc1, 0, 0, 0);
        }
    }
    __syncthreads();   // all waves done reading xs A-tile

    _Float16 hv0[16], hv1[16];
    {
        float b0 = lat_b[n0c], b1v = lat_b[n1c];
        #pragma unroll
        for (int r = 0; r < 16; ++r) {
            int row = rm + (r & 3) + 8 * (r >> 2) + 4 * lh;
            int node = n0 + row;
            float v0 = acc0[r] + b0, v1 = acc1[r] + b1v;
            hv0[r] = (_Float16)v0; hv1[r] = (_Float16)v1;
            if (node < N) {
                h[(size_t)node * HD + n0c] = v0;
                h[(size_t)node * HD + n1c] = v1;
                h16[(size_t)node * HD + n0c] = hv0[r];
                h16[(size_t)node * HD + n1c] = hv1[r];
            }
            // stage into xs (PST stride) for the PQ GEMMs
            xs[row * PST + n0c] = hv0[r];
            xs[row * PST + n1c] = hv1[r];
        }
    }
    __syncthreads();

    // P/Q GEMMs: wave wv&1 selects matrix; rows rm
    {
        const _Float16* BT  = (wv & 1) ? WbT : WaT;
        _Float16*       OUT = (wv & 1) ? Q16 : P16;
        floatx16 acc[4] = {};
        const _Float16* ap = xs + (size_t)(rm + l31) * PST + lh * 8;
        for (int ks = 0; ks < 8; ++ks) {
            half8 a = *(const half8*)(ap + ks * 16);
            #pragma unroll
            for (int i = 0; i < 4; ++i) {
                half8 b = *(const half8*)(BT + (size_t)(i * 32 + l31) * HD + ks * 16 + lh * 8);
                acc[i] = __builtin_amdgcn_mfma_f32_32x32x16_f16(a, b, acc[i], 0, 0, 0);
            }
        }
        #pragma unroll
        for (int r = 0; r < 16; ++r) {
            int row = rm + (r & 3) + 8 * (r >> 2) + 4 * lh;
            int node = n0 + row;
            if (node < N) {
                #pragma unroll
                for (int i = 0; i < 4; ++i)
                    OUT[(size_t)node * HD + i * 32 + l31] = (_Float16)acc[i][r];
            }
        }
    }
}

// ---- fused edge kernel: x1 = silu(P[a]+Q[b]+R[g] + dis@Wd); ef = silu(x1@W2+b2); scatter ----
// dis features built per-lane in registers via Chebyshev recurrence (no LDS tile).
#define PUTF(kk, val) { const int _ks = (kk) >> 4, _j = (kk) & 15;                       \
    afrag[_ks][_j & 7] = (lh == (_j >> 3)) ? (_Float16)(val) : afrag[_ks][_j & 7]; }

template <bool LAST>
__global__ __launch_bounds__(256) void k_edge(
    const int* __restrict__ eaS, const int* __restrict__ ebS,
    const int* __restrict__ egS, const float* __restrict__ fdS,
    const _Float16* __restrict__ P16, const _Float16* __restrict__ Q16,
    const _Float16* __restrict__ R16, const _Float16* __restrict__ WdT,
    const _Float16* __restrict__ W2T, const float* __restrict__ b2,
    const _Float16* __restrict__ cw1T, const float* __restrict__ cb1,
    const float* __restrict__ cw2,
    float* __restrict__ aggsum, float* __restrict__ outsum, int E)
{
    __shared__ __align__(16) _Float16 xt[64 * PST];   // pqr -> x1 -> ef (17.4 KB)
    __shared__ int   eaL[64], ebL[64], egL[64];
    __shared__ float fdlL[64][3];
    __shared__ float gateL[64];

    int tid = threadIdx.x;
    int s0  = blockIdx.x * 64;

    if (tid < 64) {
        int s = s0 + tid;
        if (s < E) {
            eaL[tid] = eaS[s]; ebL[tid] = ebS[s]; egL[tid] = egS[s];
            fdlL[tid][0] = fdS[s * 3];
            fdlL[tid][1] = fdS[s * 3 + 1];
            fdlL[tid][2] = fdS[s * 3 + 2];
        } else {
            eaL[tid] = 0; ebL[tid] = -1; egL[tid] = 0;
            fdlL[tid][0] = fdlL[tid][1] = fdlL[tid][2] = 0.f;
        }
        gateL[tid] = 0.f;
    }
    __syncthreads();

    // PQR tile: xt[row] = P[a] + Q[b] + R[g]   (vector fp16 adds)
    for (int c = tid; c < 64 * 16; c += 256) {
        int row = c >> 4, p = c & 15;
        int b = ebL[row] < 0 ? 0 : ebL[row];
        half8 pv = *(const half8*)(P16 + (size_t)eaL[row] * HD + p * 8);
        half8 qv = *(const half8*)(Q16 + (size_t)b * HD + p * 8);
        half8 rv = *(const half8*)(R16 + (size_t)egL[row] * HD + p * 8);
        half8 s = pv + qv + rv;
        *(half8*)(xt + row * PST + p * 8) = s;
    }

    int lane = tid & 63, wv = tid >> 6;
    int l31 = lane & 31, lh = lane >> 5;
    int rm = (wv >> 1) * 32, cb = (wv & 1) * 64;
    int n0c = cb + l31, n1c = cb + 32 + l31;
    int er = rm + l31;                    // this lane's edge row in the tile

    // ---- build dis A-fragment in registers (k = 16*ks + 8*lh + j) ----
    half8 afrag[4];
    #pragma unroll
    for (int i = 0; i < 4; ++i)
        #pragma unroll
        for (int j = 0; j < 8; ++j) afrag[i][j] = (_Float16)0.f;
    {
        float fdv0 = fdlL[er][0], fdv1 = fdlL[er][1], fdv2 = fdlL[er][2];
        float fdv[3] = {fdv0, fdv1, fdv2};
        #pragma unroll
        for (int d = 0; d < 3; ++d) {
            float ang = 6.283185307179586f * fdv[d];
            float s1 = __sinf(ang), c1 = __cosf(ang);
            float two_c1 = 2.f * c1;
            // w=0: sin=0 (already zero), cos=1
            PUTF(30 + 10 * d + 0, 1.0f);
            PUTF(10 * d + 1, s1);
            PUTF(30 + 10 * d + 1, c1);
            float sm2 = 0.f, sm1 = s1, cm2 = 1.f, cm1 = c1;
            #pragma unroll
            for (int wq = 2; wq < 10; ++wq) {
                float sn = two_c1 * sm1 - sm2;
                float cn = two_c1 * cm1 - cm2;
                PUTF(10 * d + wq, sn);
                PUTF(30 + 10 * d + wq, cn);
                sm2 = sm1; sm1 = sn; cm2 = cm1; cm1 = cn;
            }
        }
    }
    __syncthreads();   // PQR staging complete

    // ---- dis GEMM: K = 64, A from registers ----
    floatx16 acc0 = {}, acc1 = {};
    {
        const _Float16* bp0 = WdT + (size_t)n0c * 64 + lh * 8;
        const _Float16* bp1 = WdT + (size_t)n1c * 64 + lh * 8;
        #pragma unroll
        for (int ks = 0; ks < 4; ++ks) {
            acc0 = __builtin_amdgcn_mfma_f32_32x32x16_f16(afrag[ks], *(const half8*)(bp0 + ks * 16), acc0, 0, 0, 0);
            acc1 = __builtin_amdgcn_mfma_f32_32x32x16_f16(afrag[ks], *(const half8*)(bp1 + ks * 16), acc1, 0, 0, 0);
        }
    }
    // x1 = silu(accD + PQR), in place (lane-exclusive positions -> no barrier needed)
    #pragma unroll
    for (int r = 0; r < 16; ++r) {
        int row = rm + (r & 3) + 8 * (r >> 2) + 4 * lh;
        float v0 = acc0[r] + (float)xt[row * PST + n0c];
        float v1 = acc1[r] + (float)xt[row * PST + n1c];
        xt[row * PST + n0c] = (_Float16)silu_f(v0);
        xt[row * PST + n1c] = (_Float16)silu_f(v1);
    }
    __syncthreads();

    // ---- GEMM2: ef = silu(x1 @ W2 + b2), K = 128 ----
    acc0 = {}; acc1 = {};
    {
        const _Float16* ap  = xt + (size_t)(rm + l31) * PST + lh * 8;
        const _Float16* bp0 = W2T + (size_t)n0c * HD + lh * 8;
        const _Float16* bp1 = W2T + (size_t)n1c * HD + lh * 8;
        for (int ks = 0; ks < 8; ++ks) {
            half8 a = *(const half8*)(ap + ks * 16);
            acc0 = __builtin_amdgcn_mfma_f32_32x32x16_f16(a, *(const half8*)(bp0 + ks * 16), acc0, 0, 0, 0);
            acc1 = __builtin_amdgcn_mfma_f32_32x32x16_f16(a, *(const half8*)(bp1 + ks * 16), acc1, 0, 0, 0);
        }
    }
    __syncthreads();   // all waves done reading xt

    // ef -> xt in place (fp16)
    {
        float b20 = b2[n0c], b21 = b2[n1c];
        #pragma unroll
        for (int r = 0; r < 16; ++r) {
            int row = rm + (r & 3) + 8 * (r >> 2) + 4 * lh;
            xt[row * PST + n0c] = (_Float16)silu_f(acc0[r] + b20);
            xt[row * PST + n1c] = (_Float16)silu_f(acc1[r] + b21);
        }
    }
    __syncthreads();

    if (!LAST) {
        // run-reduced scatter (edges sorted by dest)
        int c2 = (tid & 63) * 2;
        int r0 = (tid >> 6) * 16;
        float sx = 0.f, sy = 0.f;
        int cur = -1;
        for (int r = r0; r < r0 + 16; ++r) {
            int d = ebL[r];
            float vx = (float)xt[r * PST + c2];
            float vy = (float)xt[r * PST + c2 + 1];
            if (d != cur) {
                if (cur >= 0) {
                    atomicAdd(&aggsum[(size_t)cur * HD + c2],     sx);
                    atomicAdd(&aggsum[(size_t)cur * HD + c2 + 1], sy);
                }
                cur = d; sx = vx; sy = vy;
            } else { sx += vx; sy += vy; }
        }
        if (cur >= 0) {
            atomicAdd(&aggsum[(size_t)cur * HD + c2],     sx);
            atomicAdd(&aggsum[(size_t)cur * HD + c2 + 1], sy);
        }
    } else {
        // GEMM3: g1 = silu(ef @ cw1 + cb1); gate = g1 @ cw2; scatter fd*gate
        acc0 = {}; acc1 = {};
        {
            const _Float16* ap  = xt + (size_t)(rm + l31) * PST + lh * 8;
            const _Float16* bp0 = cw1T + (size_t)n0c * HD + lh * 8;
            const _Float16* bp1 = cw1T + (size_t)n1c * HD + lh * 8;
            for (int ks = 0; ks < 8; ++ks) {
                half8 a = *(const half8*)(ap + ks * 16);
                acc0 = __builtin_amdgcn_mfma_f32_32x32x16_f16(a, *(const half8*)(bp0 + ks * 16), acc0, 0, 0, 0);
                acc1 = __builtin_amdgcn_mfma_f32_32x32x16_f16(a, *(const half8*)(bp1 + ks * 16), acc1, 0, 0, 0);
            }
        }
        float cb0 = cb1[n0c], cb1v = cb1[n1c];
        float w0 = cw2[n0c],  w1 = cw2[n1c];
        #pragma unroll
        for (int r = 0; r < 16; ++r) {
            float p = silu_f(acc0[r] + cb0) * w0 + silu_f(acc1[r] + cb1v) * w1;
            p += __shfl_xor(p, 16);
            p += __shfl_xor(p, 8);
            p += __shfl_xor(p, 4);
            p += __shfl_xor(p, 2);
            p += __shfl_xor(p, 1);
            if (l31 == 0) {
                int row = rm + (r & 3) + 8 * (r >> 2) + 4 * lh;
                atomicAdd(&gateL[row], p);
            }
        }
        __syncthreads();
        if (tid < 64) {
            int r = tid, d = ebL[r];
            if (d >= 0 && (r == 0 || ebL[r - 1] != d)) {
                float sx = 0.f, sy = 0.f, sz = 0.f;
                for (int q = r; q < 64 && ebL[q] == d; ++q) {
                    float g = gateL[q];
                    sx += fdlL[q][0] * g; sy += fdlL[q][1] * g; sz += fdlL[q][2] * g;
                }
                atomicAdd(&outsum[d * 3 + 0], sx);
                atomicAdd(&outsum[d * 3 + 1], sy);
                atomicAdd(&outsum[d * 3 + 2], sz);
            }
        }
    }
}

// ---- fused node update + next-layer P/Q ----
__global__ __launch_bounds__(256) void k_node_pq(
    float* __restrict__ h, _Float16* __restrict__ h16,
    float* __restrict__ aggsum, const float* __restrict__ deginv,
    const _Float16* __restrict__ W1T, const float* __restrict__ b1,
    const _Float16* __restrict__ W2T, const float* __restrict__ b2,
    const _Float16* __restrict__ WaT, const _Float16* __restrict__ WbT,
    _Float16* __restrict__ P16, _Float16* __restrict__ Q16, int N)
{
    __shared__ __align__(16) _Float16 xs[64 * NST];   // 33.8 KB
    _Float16* x1s = xs;

    int tid = threadIdx.x;
    int n0  = blockIdx.x * 64;

    for (int c = tid; c < 64 * 16; c += 256) {
        int row = c >> 4, p = c & 15;
        int node = n0 + row;
        uint4 v = {0, 0, 0, 0};
        if (node < N) v = *(const uint4*)(h16 + (size_t)node * HD + p * 8);
        *(uint4*)(xs + row * NST + p * 8) = v;
    }
    for (int c = tid; c < 64 * HD; c += 256) {
        int row = c >> 7, cc = c & 127;
        int node = n0 + row;
        float v = 0.f;
        if (node < N) {
            size_t gi = (size_t)node * HD + cc;
            v = aggsum[gi] * deginv[node];
            aggsum[gi] = 0.f;
        }
        xs[row * NST + HD + cc] = (_Float16)v;
    }
    __syncthreads();

    int lane = tid & 63, wv = tid >> 6;
    int l31 = lane & 31, lh = lane >> 5;
    int rm = (wv >> 1) * 32, cbase = (wv & 1) * 64;
    int n0c = cbase + l31, n1c = cbase + 32 + l31;

    floatx16 acc0 = {}, acc1 = {};
    {
        const _Float16* ap  = xs  + (size_t)(rm + l31) * NST + lh * 8;
        const _Float16* bp0 = W1T + (size_t)n0c * 256 + lh * 8;
        const _Float16* bp1 = W1T + (size_t)n1c * 256 + lh * 8;
        for (int ks = 0; ks < 16; ++ks) {
            half8 a  = *(const half8*)(ap  + ks * 16);
            acc0 = __builtin_amdgcn_mfma_f32_32x32x16_f16(a, *(const half8*)(bp0 + ks * 16), acc0, 0, 0, 0);
            acc1 = __builtin_amdgcn_mfma_f32_32x32x16_f16(a, *(const half8*)(bp1 + ks * 16), acc1, 0, 0, 0);
        }
    }
    __syncthreads();
    {
        float b10 = b1[n0c], b11 = b1[n1c];
        #pragma unroll
        for (int r = 0; r < 16; ++r) {
            int row = rm + (r & 3) + 8 * (r >> 2) + 4 * lh;
            x1s[row * XST + n0c] = (_Float16)silu_f(acc0[r] + b10);
            x1s[row * XST + n1c] = (_Float16)silu_f(acc1[r] + b11);
        }
    }
    __syncthreads();

    acc0 = {}; acc1 = {};
    {
        const _Float16* ap  = x1s + (size_t)(rm + l31) * XST + lh * 8;
        const _Float16* bp0 = W2T + (size_t)n0c * HD + lh * 8;
        const _Float16* bp1 = W2T + (size_t)n1c * HD + lh * 8;
        for (int ks = 0; ks < 8; ++ks) {
            half8 a  = *(const half8*)(ap  + ks * 16);
            acc0 = __builtin_amdgcn_mfma_f32_32x32x16_f16(a, *(const half8*)(bp0 + ks * 16), acc0, 0, 0, 0);
            acc1 = __builtin_amdgcn_mfma_f32_32x32x16_f16(a, *(const half8*)(bp1 + ks * 16), acc1, 0, 0, 0);
        }
    }
    __syncthreads();   // all waves done reading x1s before restage

    _Float16 hv0[16], hv1[16];
    {
        float b20 = b2[n0c], b21 = b2[n1c];
        #pragma unroll
        for (int r = 0; r < 16; ++r) {
            int row = rm + (r & 3) + 8 * (r >> 2) + 4 * lh;
            int node = n0 + row;
            float v0 = silu_f(acc0[r] + b20);
            float v1 = silu_f(acc1[r] + b21);
            if (node < N) {
                size_t g0 = (size_t)node * HD + n0c;
                size_t g1 = (size_t)node * HD + n1c;
                v0 += h[g0]; v1 += h[g1];
                h[g0] = v0; h[g1] = v1;
                hv0[r] = (_Float16)v0; hv1[r] = (_Float16)v1;
                h16[g0] = hv0[r]; h16[g1] = hv1[r];
            } else { hv0[r] = (_Float16)0.f; hv1[r] = (_Float16)0.f; }
            xs[row * PST + n0c] = hv0[r];
            xs[row * PST + n1c] = hv1[r];
        }
    }
    __syncthreads();

    // next-layer P/Q GEMMs from the fresh h tile
    {
        const _Float16* BT  = (wv & 1) ? WbT : WaT;
        _Float16*       OUT = (wv & 1) ? Q16 : P16;
        floatx16 acc[4] = {};
        const _Float16* ap = xs + (size_t)(rm + l31) * PST + lh * 8;
        for (int ks = 0; ks < 8; ++ks) {
            half8 a = *(const half8*)(ap + ks * 16);
            #pragma unroll
            for (int i = 0; i < 4; ++i) {
                half8 b = *(const half8*)(BT + (size_t)(i * 32 + l31) * HD + ks * 16 + lh * 8);
                acc[i] = __builtin_amdgcn_mfma_f32_32x32x16_f16(a, b, acc[i], 0, 0, 0);
            }
        }
        #pragma unroll
        for (int r = 0; r < 16; ++r) {
            int row = rm + (r & 3) + 8 * (r >> 2) + 4 * lh;
            int node = n0 + row;
            if (node < N) {
                #pragma unroll
                for (int i = 0; i < 4; ++i)
                    OUT[(size_t)node * HD + i * 32 + l31] = (_Float16)acc[i][r];
            }
        }
    }
}

// ---------------- launcher ----------------
extern "C" void kernel_launch(void* const* d_in, const int* in_sizes, int n_in,
                              void* d_out, int out_size, void* d_ws, size_t ws_size,
                              hipStream_t stream)
{
    const int*   at    = (const int*)  d_in[0];
    const float* t     = (const float*)d_in[1];
    const float* fc    = (const float*)d_in[2];
    const int*   ei    = (const int*)  d_in[3];
    const float* lat   = (const float*)d_in[4];
    const int*   n2g   = (const int*)  d_in[5];
    const float* embed = (const float*)d_in[6];
    const float* lat_w = (const float*)d_in[7];
    const float* lat_b = (const float*)d_in[8];
    const float* ew1   = (const float*)d_in[9];
    const float* eb1   = (const float*)d_in[10];
    const float* ew2   = (const float*)d_in[11];
    const float* eb2   = (const float*)d_in[12];
    const float* nw1   = (const float*)d_in[13];
    const float* nb1   = (const float*)d_in[14];
    const float* nw2   = (const float*)d_in[15];
    const float* nb2   = (const float*)d_in[16];
    const float* cw1   = (const float*)d_in[17];
    const float* cb1   = (const float*)d_in[18];
    const float* cw2   = (const float*)d_in[19];

    int N = in_sizes[0];
    int E = in_sizes[3] / 2;
    int G = in_sizes[4] / 9;

    // ---- workspace carve ----
    char* p = (char*)d_ws;
    float* h      = (float*)p;  p += (size_t)N * HD * 4;
    float* aggsum = (float*)p;  p += (size_t)N * HD * 4;   // zeroed below
    float* outsum = (float*)p;  p += (size_t)N * 3 * 4;    // zeroed below
    int*   cnt    = (int*)p;    p += (size_t)N * 4;        // zeroed below
    int*   head   = (int*)p;    p += (size_t)N * 4;
    float* deginv = (float*)p;  p += (size_t)N * 4;
    float* latip  = (float*)p;  p += (size_t)G * 9 * 4;
    int*   perm   = (int*)p;    p += (size_t)E * 4;
    int*   eaS    = (int*)p;    p += (size_t)E * 4;
    int*   ebS    = (int*)p;    p += (size_t)E * 4;
    int*   egS    = (int*)p;    p += (size_t)E * 4;
    float* fdS    = (float*)p;  p += (size_t)E * 3 * 4;
    _Float16* h16   = (_Float16*)p; p += (size_t)N * HD * 2;
    _Float16* P16   = (_Float16*)p; p += (size_t)N * HD * 2;
    _Float16* Q16   = (_Float16*)p; p += (size_t)N * HD * 2;
    _Float16* w1aT  = (_Float16*)p; p += (size_t)4 * HD * HD * 2;
    _Float16* w1bT  = (_Float16*)p; p += (size_t)4 * HD * HD * 2;
    _Float16* wdT   = (_Float16*)p; p += (size_t)4 * HD * 64 * 2;
    _Float16* w2T   = (_Float16*)p; p += (size_t)4 * HD * HD * 2;
    _Float16* nw1T  = (_Float16*)p; p += (size_t)3 * HD * 256 * 2;
    _Float16* nw2T  = (_Float16*)p; p += (size_t)3 * HD * HD * 2;
    _Float16* cw1T  = (_Float16*)p; p += (size_t)HD * HD * 2;
    _Float16* latwT = (_Float16*)p; p += (size_t)HD * 400 * 2;
    _Float16* R16   = (_Float16*)p; p += (size_t)4 * G * HD * 2;

    // zero aggsum|outsum|cnt (contiguous)
    hipMemsetAsync(aggsum, 0, ((size_t)N * HD + (size_t)N * 3 + N) * 4, stream);

    // weight prep (fp16, transposed, K-padded)
    {
        int tot;
        tot = 4 * HD * HD;  k_wprep<<<(tot+255)/256, 256, 0, stream>>>(ew1, w1aT, EIN, 0,   128, HD, HD, 4);
        tot = 4 * HD * HD;  k_wprep<<<(tot+255)/256, 256, 0, stream>>>(ew1, w1bT, EIN, 128, 128, HD, HD, 4);
        tot = 4 * HD * 64;  k_wprep<<<(tot+255)/256, 256, 0, stream>>>(ew1, wdT,  EIN, 265, 60,  HD, 64, 4);
        tot = 4 * HD * HD;  k_wprep<<<(tot+255)/256, 256, 0, stream>>>(ew2, w2T,  HD,  0,  128, HD, HD, 4);
        tot = 3 * HD * 256; k_wprep<<<(tot+255)/256, 256, 0, stream>>>(nw1, nw1T, 256, 0,  256, HD, 256, 3);
        tot = 3 * HD * HD;  k_wprep<<<(tot+255)/256, 256, 0, stream>>>(nw2, nw2T, HD,  0,  128, HD, HD, 3);
        tot = 1 * HD * HD;  k_wprep<<<(tot+255)/256, 256, 0, stream>>>(cw1, cw1T, HD,  0,  128, HD, HD, 1);
        tot = HD * 400;     k_wprep<<<(tot+255)/256, 256, 0, stream>>>(lat_w, latwT, 384, 0, 384, HD, 400, 1);
    }

    k_latip  <<<(G * 9 + 255) / 256, 256, 0, stream>>>(lat, latip, G);
    k_hist   <<<(E + 255) / 256,     256, 0, stream>>>(ei + E, cnt, E);
    k_scan   <<<1, 1024, 0, stream>>>(cnt, head, N);
    k_deginv <<<(N + 255) / 256,     256, 0, stream>>>(cnt, deginv, N);
    k_scatter<<<(E + 255) / 256,     256, 0, stream>>>(ei + E, head, perm, E);
    k_esort  <<<(E + 255) / 256,     256, 0, stream>>>(ei, n2g, fc, perm, eaS, ebS, egS, fdS, E);
    k_rlat   <<<(4 * G * HD + 255) / 256, 256, 0, stream>>>(latip, ew1, eb1, R16, G);
    k_init_pq<<<(N + 63) / 64, 256, 0, stream>>>(at, t, embed, latwT, lat_b, h, h16,
                                                 w1aT, w1bT, P16, Q16, N);

    int eblocks = (E + 63) / 64;
    int nblocks = (N + 63) / 64;
    for (int l = 0; l < 3; ++l) {
        k_edge<false><<<eblocks, 256, 0, stream>>>(eaS, ebS, egS, fdS, P16, Q16,
            R16 + (size_t)l * G * HD, wdT + (size_t)l * HD * 64,
            w2T + (size_t)l * HD * HD, eb2 + l * HD,
            cw1T, cb1, cw2, aggsum, outsum, E);
        k_node_pq<<<nblocks, 256, 0, stream>>>(h, h16, aggsum, deginv,
            nw1T + (size_t)l * HD * 256, nb1 + l * HD,
            nw2T + (size_t)l * HD * HD,  nb2 + l * HD,
            w1aT + (size_t)(l + 1) * HD * HD, w1bT + (size_t)(l + 1) * HD * HD,
            P16, Q16, N);
    }
    k_edge<true><<<eblocks, 256, 0, stream>>>(eaS, ebS, egS, fdS, P16, Q16,
        R16 + (size_t)3 * G * HD, wdT + (size_t)3 * HD * 64,
        w2T + (size_t)3 * HD * HD, eb2 + 3 * HD,
        cw1T, cb1, cw2, aggsum, outsum, E);

    k_fin<<<(N * 3 + 255) / 256, 256, 0, stream>>>(outsum, deginv, (float*)d_out, N);
}